// Round 1
// baseline (4575.709 us; speedup 1.0000x reference)
//
#include <hip/hip_runtime.h>
#include <hip/hip_bf16.h>
#include <math.h>

#define S_LEN 2048
#define HID   1024
#define NHEAD 16
#define KVH   4
#define HD    64
#define FF    1024
#define NE    8
#define NL    2

// ---- workspace layout (float offsets) ----
#define OFF_H    0
#define OFF_XN   (OFF_H    + S_LEN*HID)
#define OFF_Q    (OFF_XN   + S_LEN*HID)
#define OFF_K    (OFF_Q    + S_LEN*HID)
#define OFF_V    (OFF_K    + S_LEN*KVH*HD)
#define OFF_AO   (OFF_V    + S_LEN*KVH*HD)
#define OFF_COS  (OFF_AO   + S_LEN*HID)
#define OFF_SIN  (OFF_COS  + S_LEN*32)
#define OFF_WT   (OFF_SIN  + S_LEN*32)
#define OFF_ABUF (OFF_WT   + NE*S_LEN)
#define OFF_INT  (OFF_ABUF + NE*S_LEN*FF)

// ---------------- RoPE tables ----------------
__global__ void rope_tables_kernel(float* __restrict__ cosb, float* __restrict__ sinb) {
    int gid = blockIdx.x * 256 + threadIdx.x;     // S_LEN*32 total
    int t = gid >> 5, i = gid & 31;
    float invf = powf(1.0e6f, -(float)i / 32.0f);
    float ang = (float)t * invf;
    cosb[gid] = cosf(ang);
    sinb[gid] = sinf(ang);
}

// ---------------- RMSNorm ----------------
__global__ __launch_bounds__(256) void rmsnorm_kernel(const float* __restrict__ x,
                                                      const float* __restrict__ w,
                                                      float* __restrict__ out) {
    int row = blockIdx.x;
    const float4* xr = (const float4*)(x + (size_t)row * HID);
    float4 xv = xr[threadIdx.x];
    float ss = xv.x*xv.x + xv.y*xv.y + xv.z*xv.z + xv.w*xv.w;
    for (int off = 32; off; off >>= 1) ss += __shfl_xor(ss, off);
    __shared__ float sred[4];
    if ((threadIdx.x & 63) == 0) sred[threadIdx.x >> 6] = ss;
    __syncthreads();
    float tot = sred[0] + sred[1] + sred[2] + sred[3];
    float scale = rsqrtf(tot * (1.0f / (float)HID) + 1e-5f);
    float4 wv = ((const float4*)w)[threadIdx.x];
    float4 o;
    o.x = xv.x * scale * wv.x; o.y = xv.y * scale * wv.y;
    o.z = xv.z * scale * wv.z; o.w = xv.w * scale * wv.w;
    ((float4*)(out + (size_t)row * HID))[threadIdx.x] = o;
}

// ---------------- generic NT GEMM: C[M,N] = A[M,K] @ B[N,K]^T (+resid) ----------------
__global__ __launch_bounds__(256) void gemm_nt_kernel(const float* __restrict__ A,
                                                      const float* __restrict__ B,
                                                      float* __restrict__ C,
                                                      const float* __restrict__ resid,
                                                      int N, int Kd) {
    __shared__ float As[16][65];
    __shared__ float Bs[16][65];
    int tid = threadIdx.x;
    int m0 = blockIdx.y * 64, n0 = blockIdx.x * 64;
    int lr = tid >> 2;
    int lc = (tid & 3) << 2;
    int ty = tid >> 4, tx = tid & 15;
    float acc[4][4] = {};
    for (int k0 = 0; k0 < Kd; k0 += 16) {
        float4 av = *(const float4*)(A + (size_t)(m0 + lr) * Kd + k0 + lc);
        float4 bv = *(const float4*)(B + (size_t)(n0 + lr) * Kd + k0 + lc);
        __syncthreads();
        As[lc+0][lr] = av.x; As[lc+1][lr] = av.y; As[lc+2][lr] = av.z; As[lc+3][lr] = av.w;
        Bs[lc+0][lr] = bv.x; Bs[lc+1][lr] = bv.y; Bs[lc+2][lr] = bv.z; Bs[lc+3][lr] = bv.w;
        __syncthreads();
        #pragma unroll
        for (int kk = 0; kk < 16; ++kk) {
            float a0 = As[kk][ty*4+0], a1 = As[kk][ty*4+1], a2 = As[kk][ty*4+2], a3 = As[kk][ty*4+3];
            float b0 = Bs[kk][tx*4+0], b1 = Bs[kk][tx*4+1], b2 = Bs[kk][tx*4+2], b3 = Bs[kk][tx*4+3];
            acc[0][0] += a0*b0; acc[0][1] += a0*b1; acc[0][2] += a0*b2; acc[0][3] += a0*b3;
            acc[1][0] += a1*b0; acc[1][1] += a1*b1; acc[1][2] += a1*b2; acc[1][3] += a1*b3;
            acc[2][0] += a2*b0; acc[2][1] += a2*b1; acc[2][2] += a2*b2; acc[2][3] += a2*b3;
            acc[3][0] += a3*b0; acc[3][1] += a3*b1; acc[3][2] += a3*b2; acc[3][3] += a3*b3;
        }
    }
    #pragma unroll
    for (int i = 0; i < 4; ++i) {
        #pragma unroll
        for (int j = 0; j < 4; ++j) {
            int m = m0 + ty*4 + i, n = n0 + tx*4 + j;
            float val = acc[i][j];
            if (resid) val += resid[(size_t)m * N + n];
            C[(size_t)m * N + n] = val;
        }
    }
}

// ---------------- RoPE apply (in-place, q or k) ----------------
__global__ void rope_apply_kernel(float* __restrict__ p, const float* __restrict__ cosb,
                                  const float* __restrict__ sinb, int nh, int total) {
    int gid = blockIdx.x * 256 + threadIdx.x;
    if (gid >= total) return;
    int per = nh * 32;
    int t = gid / per, r = gid % per;
    int hh = r >> 5, i = r & 31;
    float c = cosb[t*32 + i], s = sinb[t*32 + i];
    float* base = p + (size_t)t * (nh * HD) + hh * HD + i;
    float a = base[0], b = base[32];
    base[0]  = a * c - b * s;
    base[32] = b * c + a * s;
}

// ---------------- causal attention: one wave per (head,row) ----------------
__global__ __launch_bounds__(256) void attn_kernel(const float* __restrict__ q,
                                                   const float* __restrict__ k,
                                                   const float* __restrict__ v,
                                                   float* __restrict__ ao) {
    __shared__ float sc[4][S_LEN];
    __shared__ float qs[4][64];
    int wid = threadIdx.x >> 6;
    int lane = threadIdx.x & 63;
    int gw = blockIdx.x * 4 + wid;
    int head = gw >> 11;           // S_LEN rows per head
    int row = gw & (S_LEN - 1);
    int kvh = head >> 2;
    qs[wid][lane] = q[(size_t)row * HID + head * HD + lane];
    __syncthreads();
    int nk = row + 1;
    // phase 1: scores
    float mx = -INFINITY;
    for (int key = lane; key < nk; key += 64) {
        const float4* kr = (const float4*)(k + (size_t)key * (KVH*HD) + kvh * HD);
        float d = 0.f;
        #pragma unroll
        for (int j = 0; j < 16; ++j) {
            float4 k4 = kr[j];
            d += qs[wid][4*j+0]*k4.x + qs[wid][4*j+1]*k4.y + qs[wid][4*j+2]*k4.z + qs[wid][4*j+3]*k4.w;
        }
        d *= 0.125f;
        sc[wid][key] = d;
        mx = fmaxf(mx, d);
    }
    for (int off = 32; off; off >>= 1) mx = fmaxf(mx, __shfl_xor(mx, off));
    // phase 2: exp + sum
    float sum = 0.f;
    for (int key = lane; key < nk; key += 64) {
        float e = __expf(sc[wid][key] - mx);
        sc[wid][key] = e;
        sum += e;
    }
    for (int off = 32; off; off >>= 1) sum += __shfl_xor(sum, off);
    float inv = 1.0f / sum;
    // phase 3: lane = dim
    const float* vb = v + kvh * HD + lane;
    float o0 = 0.f, o1 = 0.f, o2 = 0.f, o3 = 0.f;
    int key = 0;
    for (; key + 4 <= nk; key += 4) {
        o0 += sc[wid][key+0] * vb[(size_t)(key+0) * (KVH*HD)];
        o1 += sc[wid][key+1] * vb[(size_t)(key+1) * (KVH*HD)];
        o2 += sc[wid][key+2] * vb[(size_t)(key+2) * (KVH*HD)];
        o3 += sc[wid][key+3] * vb[(size_t)(key+3) * (KVH*HD)];
    }
    for (; key < nk; ++key) o0 += sc[wid][key] * vb[(size_t)key * (KVH*HD)];
    ao[(size_t)row * HID + head * HD + lane] = ((o0+o1)+(o2+o3)) * inv;
}

// ---------------- gate + top-2 routing ----------------
__global__ __launch_bounds__(64) void gate_topk_kernel(const float* __restrict__ xn,
                                                       const float* __restrict__ gw,
                                                       int* __restrict__ cnt,
                                                       int* __restrict__ idx,
                                                       float* __restrict__ wt) {
    int t = blockIdx.x, lane = threadIdx.x;
    float acc[NE] = {};
    for (int i = lane; i < HID; i += 64) {
        float x = xn[(size_t)t * HID + i];
        #pragma unroll
        for (int e = 0; e < NE; ++e) acc[e] += x * gw[e * HID + i];
    }
    #pragma unroll
    for (int e = 0; e < NE; ++e)
        for (int off = 32; off; off >>= 1) acc[e] += __shfl_xor(acc[e], off);
    if (lane == 0) {
        float mx = acc[0];
        #pragma unroll
        for (int e = 1; e < NE; ++e) mx = fmaxf(mx, acc[e]);
        float p[NE];
        #pragma unroll
        for (int e = 0; e < NE; ++e) p[e] = __expf(acc[e] - mx);
        int i0 = 0;
        #pragma unroll
        for (int e = 1; e < NE; ++e) if (p[e] > p[i0]) i0 = e;
        int i1 = -1;
        #pragma unroll
        for (int e = 0; e < NE; ++e) if (e != i0 && (i1 < 0 || p[e] > p[i1])) i1 = e;
        float w0 = p[i0], w1 = p[i1];
        float inv = 1.0f / (w0 + w1);
        int s0 = atomicAdd(&cnt[i0], 1);
        idx[i0 * S_LEN + s0] = t; wt[i0 * S_LEN + s0] = w0 * inv;
        int s1 = atomicAdd(&cnt[i1], 1);
        idx[i1 * S_LEN + s1] = t; wt[i1 * S_LEN + s1] = w1 * inv;
    }
}

// ---------------- MoE mlp1: a = silu(x@w1^T) * (x@w3^T), gathered rows ----------------
__global__ __launch_bounds__(256) void moe_mlp1_kernel(const float* __restrict__ X,
                                                       const float* __restrict__ W1,
                                                       const float* __restrict__ W3,
                                                       const int* __restrict__ cnt,
                                                       const int* __restrict__ idx,
                                                       float* __restrict__ abuf) {
    int e = blockIdx.z;
    int ne = cnt[e];
    int m0 = blockIdx.y * 64;
    if (m0 >= ne) return;
    int f0 = blockIdx.x * 64;
    __shared__ float As[16][65], B1s[16][65], B3s[16][65];
    __shared__ int rows[64];
    int tid = threadIdx.x;
    if (tid < 64) {
        int slot = m0 + tid;
        rows[tid] = (slot < ne) ? idx[e * S_LEN + slot] : 0;
    }
    __syncthreads();
    const float* w1e = W1 + (size_t)e * FF * HID;
    const float* w3e = W3 + (size_t)e * FF * HID;
    int lr = tid >> 2;
    int lc = (tid & 3) << 2;
    int ty = tid >> 4, tx = tid & 15;
    int arow = rows[lr];
    float accg[4][4] = {}, accu[4][4] = {};
    for (int k0 = 0; k0 < HID; k0 += 16) {
        float4 av  = *(const float4*)(X   + (size_t)arow * HID + k0 + lc);
        float4 b1v = *(const float4*)(w1e + (size_t)(f0 + lr) * HID + k0 + lc);
        float4 b3v = *(const float4*)(w3e + (size_t)(f0 + lr) * HID + k0 + lc);
        __syncthreads();
        As[lc+0][lr]  = av.x;  As[lc+1][lr]  = av.y;  As[lc+2][lr]  = av.z;  As[lc+3][lr]  = av.w;
        B1s[lc+0][lr] = b1v.x; B1s[lc+1][lr] = b1v.y; B1s[lc+2][lr] = b1v.z; B1s[lc+3][lr] = b1v.w;
        B3s[lc+0][lr] = b3v.x; B3s[lc+1][lr] = b3v.y; B3s[lc+2][lr] = b3v.z; B3s[lc+3][lr] = b3v.w;
        __syncthreads();
        #pragma unroll
        for (int kk = 0; kk < 16; ++kk) {
            float a0 = As[kk][ty*4+0], a1 = As[kk][ty*4+1], a2 = As[kk][ty*4+2], a3 = As[kk][ty*4+3];
            float g0 = B1s[kk][tx*4+0], g1 = B1s[kk][tx*4+1], g2 = B1s[kk][tx*4+2], g3 = B1s[kk][tx*4+3];
            float u0 = B3s[kk][tx*4+0], u1 = B3s[kk][tx*4+1], u2 = B3s[kk][tx*4+2], u3 = B3s[kk][tx*4+3];
            accg[0][0]+=a0*g0; accg[0][1]+=a0*g1; accg[0][2]+=a0*g2; accg[0][3]+=a0*g3;
            accg[1][0]+=a1*g0; accg[1][1]+=a1*g1; accg[1][2]+=a1*g2; accg[1][3]+=a1*g3;
            accg[2][0]+=a2*g0; accg[2][1]+=a2*g1; accg[2][2]+=a2*g2; accg[2][3]+=a2*g3;
            accg[3][0]+=a3*g0; accg[3][1]+=a3*g1; accg[3][2]+=a3*g2; accg[3][3]+=a3*g3;
            accu[0][0]+=a0*u0; accu[0][1]+=a0*u1; accu[0][2]+=a0*u2; accu[0][3]+=a0*u3;
            accu[1][0]+=a1*u0; accu[1][1]+=a1*u1; accu[1][2]+=a1*u2; accu[1][3]+=a1*u3;
            accu[2][0]+=a2*u0; accu[2][1]+=a2*u1; accu[2][2]+=a2*u2; accu[2][3]+=a2*u3;
            accu[3][0]+=a3*u0; accu[3][1]+=a3*u1; accu[3][2]+=a3*u2; accu[3][3]+=a3*u3;
        }
    }
    #pragma unroll
    for (int i = 0; i < 4; ++i) {
        int slot = m0 + ty*4 + i;
        if (slot >= ne) continue;
        #pragma unroll
        for (int j = 0; j < 4; ++j) {
            float g = accg[i][j], u = accu[i][j];
            float a = g * (1.0f / (1.0f + __expf(-g))) * u;
            abuf[(size_t)e * S_LEN * FF + (size_t)slot * FF + f0 + tx*4 + j] = a;
        }
    }
}

// ---------------- MoE mlp2: h += wt * (a @ w2^T) ----------------
__global__ __launch_bounds__(256) void moe_mlp2_kernel(const float* __restrict__ abuf,
                                                       const float* __restrict__ W2,
                                                       const int* __restrict__ cnt,
                                                       const int* __restrict__ idx,
                                                       const float* __restrict__ wt,
                                                       float* __restrict__ hbuf) {
    int e = blockIdx.z;
    int ne = cnt[e];
    int m0 = blockIdx.y * 64;
    if (m0 >= ne) return;
    int n0 = blockIdx.x * 64;
    __shared__ float As[16][65], Bs[16][65];
    const float* Ae = abuf + (size_t)e * S_LEN * FF;
    const float* w2e = W2 + (size_t)e * HID * FF;
    int tid = threadIdx.x;
    int lr = tid >> 2;
    int lc = (tid & 3) << 2;
    int ty = tid >> 4, tx = tid & 15;
    float acc[4][4] = {};
    for (int k0 = 0; k0 < FF; k0 += 16) {
        float4 av = *(const float4*)(Ae  + (size_t)(m0 + lr) * FF + k0 + lc);
        float4 bv = *(const float4*)(w2e + (size_t)(n0 + lr) * FF + k0 + lc);
        __syncthreads();
        As[lc+0][lr] = av.x; As[lc+1][lr] = av.y; As[lc+2][lr] = av.z; As[lc+3][lr] = av.w;
        Bs[lc+0][lr] = bv.x; Bs[lc+1][lr] = bv.y; Bs[lc+2][lr] = bv.z; Bs[lc+3][lr] = bv.w;
        __syncthreads();
        #pragma unroll
        for (int kk = 0; kk < 16; ++kk) {
            float a0 = As[kk][ty*4+0], a1 = As[kk][ty*4+1], a2 = As[kk][ty*4+2], a3 = As[kk][ty*4+3];
            float b0 = Bs[kk][tx*4+0], b1 = Bs[kk][tx*4+1], b2 = Bs[kk][tx*4+2], b3 = Bs[kk][tx*4+3];
            acc[0][0] += a0*b0; acc[0][1] += a0*b1; acc[0][2] += a0*b2; acc[0][3] += a0*b3;
            acc[1][0] += a1*b0; acc[1][1] += a1*b1; acc[1][2] += a1*b2; acc[1][3] += a1*b3;
            acc[2][0] += a2*b0; acc[2][1] += a2*b1; acc[2][2] += a2*b2; acc[2][3] += a2*b3;
            acc[3][0] += a3*b0; acc[3][1] += a3*b1; acc[3][2] += a3*b2; acc[3][3] += a3*b3;
        }
    }
    #pragma unroll
    for (int i = 0; i < 4; ++i) {
        int slot = m0 + ty*4 + i;
        if (slot >= ne) continue;
        int tok = idx[e * S_LEN + slot];
        float wv = wt[e * S_LEN + slot];
        #pragma unroll
        for (int j = 0; j < 4; ++j) {
            atomicAdd(&hbuf[(size_t)tok * HID + n0 + tx*4 + j], acc[i][j] * wv);
        }
    }
}

extern "C" void kernel_launch(void* const* d_in, const int* in_sizes, int n_in,
                              void* d_out, int out_size, void* d_ws, size_t ws_size,
                              hipStream_t stream) {
    const float* emb = (const float*)d_in[0];
    const float* ln1 = (const float*)d_in[1];
    const float* ln2 = (const float*)d_in[2];
    const float* fln = (const float*)d_in[3];
    const float* qw  = (const float*)d_in[4];
    const float* kw  = (const float*)d_in[5];
    const float* vw  = (const float*)d_in[6];
    const float* ow  = (const float*)d_in[7];
    const float* gw  = (const float*)d_in[8];
    const float* w1  = (const float*)d_in[9];
    const float* w2  = (const float*)d_in[10];
    const float* w3  = (const float*)d_in[11];

    float* ws   = (float*)d_ws;
    float* h    = ws + OFF_H;
    float* xn   = ws + OFF_XN;
    float* q    = ws + OFF_Q;
    float* kb   = ws + OFF_K;
    float* vb   = ws + OFF_V;
    float* ao   = ws + OFF_AO;
    float* cosb = ws + OFF_COS;
    float* sinb = ws + OFF_SIN;
    float* wt   = ws + OFF_WT;
    float* abuf = ws + OFF_ABUF;
    int*   cnt  = (int*)(ws + OFF_INT);
    int*   idx  = cnt + 8;

    hipMemcpyAsync(h, emb, (size_t)S_LEN * HID * sizeof(float), hipMemcpyDeviceToDevice, stream);
    rope_tables_kernel<<<S_LEN * 32 / 256, 256, 0, stream>>>(cosb, sinb);

    for (int l = 0; l < NL; ++l) {
        rmsnorm_kernel<<<S_LEN, 256, 0, stream>>>(h, ln1 + l * HID, xn);
        gemm_nt_kernel<<<dim3(16, 32), 256, 0, stream>>>(xn, qw + (size_t)l * HID * HID, q, nullptr, HID, HID);
        gemm_nt_kernel<<<dim3(4, 32), 256, 0, stream>>>(xn, kw + (size_t)l * KVH * HD * HID, kb, nullptr, KVH * HD, HID);
        gemm_nt_kernel<<<dim3(4, 32), 256, 0, stream>>>(xn, vw + (size_t)l * KVH * HD * HID, vb, nullptr, KVH * HD, HID);
        rope_apply_kernel<<<(S_LEN * NHEAD * 32) / 256, 256, 0, stream>>>(q, cosb, sinb, NHEAD, S_LEN * NHEAD * 32);
        rope_apply_kernel<<<(S_LEN * KVH * 32) / 256, 256, 0, stream>>>(kb, cosb, sinb, KVH, S_LEN * KVH * 32);
        attn_kernel<<<NHEAD * S_LEN / 4, 256, 0, stream>>>(q, kb, vb, ao);
        gemm_nt_kernel<<<dim3(16, 32), 256, 0, stream>>>(ao, ow + (size_t)l * HID * HID, h, h, HID, HID);
        rmsnorm_kernel<<<S_LEN, 256, 0, stream>>>(h, ln2 + l * HID, xn);
        hipMemsetAsync(cnt, 0, 8 * sizeof(int), stream);
        gate_topk_kernel<<<S_LEN, 64, 0, stream>>>(xn, gw + (size_t)l * NE * HID, cnt, idx, wt);
        moe_mlp1_kernel<<<dim3(16, 32, 8), 256, 0, stream>>>(xn, w1 + (size_t)l * NE * FF * HID,
                                                             w3 + (size_t)l * NE * FF * HID, cnt, idx, abuf);
        moe_mlp2_kernel<<<dim3(16, 32, 8), 256, 0, stream>>>(abuf, w2 + (size_t)l * NE * HID * FF, cnt, idx, wt, h);
    }
    rmsnorm_kernel<<<S_LEN, 256, 0, stream>>>(h, fln, (float*)d_out);
}

// Round 2
// 2143.692 us; speedup vs baseline: 2.1345x; 2.1345x over previous
//
#include <hip/hip_runtime.h>
#include <hip/hip_bf16.h>
#include <math.h>

#define S_LEN 2048
#define HID   1024
#define NHEAD 16
#define KVH   4
#define HD    64
#define FF    1024
#define NE    8
#define NL    2

// ---- workspace layout (float offsets) ----
#define OFF_H    0
#define OFF_XN   (OFF_H    + S_LEN*HID)
#define OFF_Q    (OFF_XN   + S_LEN*HID)
#define OFF_K    (OFF_Q    + S_LEN*HID)
#define OFF_V    (OFF_K    + S_LEN*KVH*HD)
#define OFF_AO   (OFF_V    + S_LEN*KVH*HD)
#define OFF_COS  (OFF_AO   + S_LEN*HID)
#define OFF_SIN  (OFF_COS  + S_LEN*32)
#define OFF_WT   (OFF_SIN  + S_LEN*32)
#define OFF_ABUF (OFF_WT   + NE*S_LEN)
#define OFF_INT  (OFF_ABUF + NE*S_LEN*FF)

typedef __attribute__((ext_vector_type(8))) short bf16x8;
typedef __attribute__((ext_vector_type(4))) float f32x4;

__device__ __forceinline__ short f2b(float f) {
    union { __hip_bfloat16 b; short s; } u;
    u.b = __float2bfloat16(f);
    return u.s;
}

// ---------------- RoPE tables ----------------
__global__ void rope_tables_kernel(float* __restrict__ cosb, float* __restrict__ sinb) {
    int gid = blockIdx.x * 256 + threadIdx.x;     // S_LEN*32 total
    int t = gid >> 5, i = gid & 31;
    float invf = powf(1.0e6f, -(float)i / 32.0f);
    float ang = (float)t * invf;
    cosb[gid] = cosf(ang);
    sinb[gid] = sinf(ang);
}

// ---------------- RMSNorm ----------------
__global__ __launch_bounds__(256) void rmsnorm_kernel(const float* __restrict__ x,
                                                      const float* __restrict__ w,
                                                      float* __restrict__ out) {
    int row = blockIdx.x;
    const float4* xr = (const float4*)(x + (size_t)row * HID);
    float4 xv = xr[threadIdx.x];
    float ss = xv.x*xv.x + xv.y*xv.y + xv.z*xv.z + xv.w*xv.w;
    for (int off = 32; off; off >>= 1) ss += __shfl_xor(ss, off);
    __shared__ float sred[4];
    if ((threadIdx.x & 63) == 0) sred[threadIdx.x >> 6] = ss;
    __syncthreads();
    float tot = sred[0] + sred[1] + sred[2] + sred[3];
    float scale = rsqrtf(tot * (1.0f / (float)HID) + 1e-5f);
    float4 wv = ((const float4*)w)[threadIdx.x];
    float4 o;
    o.x = xv.x * scale * wv.x; o.y = xv.y * scale * wv.y;
    o.z = xv.z * scale * wv.z; o.w = xv.w * scale * wv.w;
    ((float4*)(out + (size_t)row * HID))[threadIdx.x] = o;
}

// ---------------- generic NT GEMM: C[M,N] = A[M,K] @ B[N,K]^T (+resid) ----------------
__global__ __launch_bounds__(256) void gemm_nt_kernel(const float* __restrict__ A,
                                                      const float* __restrict__ B,
                                                      float* __restrict__ C,
                                                      const float* __restrict__ resid,
                                                      int N, int Kd) {
    __shared__ float As[16][65];
    __shared__ float Bs[16][65];
    int tid = threadIdx.x;
    int m0 = blockIdx.y * 64, n0 = blockIdx.x * 64;
    int lr = tid >> 2;
    int lc = (tid & 3) << 2;
    int ty = tid >> 4, tx = tid & 15;
    float acc[4][4] = {};
    for (int k0 = 0; k0 < Kd; k0 += 16) {
        float4 av = *(const float4*)(A + (size_t)(m0 + lr) * Kd + k0 + lc);
        float4 bv = *(const float4*)(B + (size_t)(n0 + lr) * Kd + k0 + lc);
        __syncthreads();
        As[lc+0][lr] = av.x; As[lc+1][lr] = av.y; As[lc+2][lr] = av.z; As[lc+3][lr] = av.w;
        Bs[lc+0][lr] = bv.x; Bs[lc+1][lr] = bv.y; Bs[lc+2][lr] = bv.z; Bs[lc+3][lr] = bv.w;
        __syncthreads();
        #pragma unroll
        for (int kk = 0; kk < 16; ++kk) {
            float a0 = As[kk][ty*4+0], a1 = As[kk][ty*4+1], a2 = As[kk][ty*4+2], a3 = As[kk][ty*4+3];
            float b0 = Bs[kk][tx*4+0], b1 = Bs[kk][tx*4+1], b2 = Bs[kk][tx*4+2], b3 = Bs[kk][tx*4+3];
            acc[0][0] += a0*b0; acc[0][1] += a0*b1; acc[0][2] += a0*b2; acc[0][3] += a0*b3;
            acc[1][0] += a1*b0; acc[1][1] += a1*b1; acc[1][2] += a1*b2; acc[1][3] += a1*b3;
            acc[2][0] += a2*b0; acc[2][1] += a2*b1; acc[2][2] += a2*b2; acc[2][3] += a2*b3;
            acc[3][0] += a3*b0; acc[3][1] += a3*b1; acc[3][2] += a3*b2; acc[3][3] += a3*b3;
        }
    }
    #pragma unroll
    for (int i = 0; i < 4; ++i) {
        #pragma unroll
        for (int j = 0; j < 4; ++j) {
            int m = m0 + ty*4 + i, n = n0 + tx*4 + j;
            float val = acc[i][j];
            if (resid) val += resid[(size_t)m * N + n];
            C[(size_t)m * N + n] = val;
        }
    }
}

// ---------------- RoPE apply (in-place, q or k) ----------------
__global__ void rope_apply_kernel(float* __restrict__ p, const float* __restrict__ cosb,
                                  const float* __restrict__ sinb, int nh, int total) {
    int gid = blockIdx.x * 256 + threadIdx.x;
    if (gid >= total) return;
    int per = nh * 32;
    int t = gid / per, r = gid % per;
    int hh = r >> 5, i = r & 31;
    float c = cosb[t*32 + i], s = sinb[t*32 + i];
    float* base = p + (size_t)t * (nh * HD) + hh * HD + i;
    float a = base[0], b = base[32];
    base[0]  = a * c - b * s;
    base[32] = b * c + a * s;
}

// ---------------- MFMA flash attention ----------------
// block = (head, q-tile of 64 rows); 4 waves x 16 rows; K/V tiles of 64 keys.
// 16x16x32 bf16 MFMA. A-frag: row=lane&15, k=8*(lane>>4)+i. B-frag: col=lane&15,
// k=8*(lane>>4)+i. C/D: col=lane&15, row=4*(lane>>4)+reg (m89-verified).
__global__ __launch_bounds__(256) void attn_mfma_kernel(const float* __restrict__ q,
                                                        const float* __restrict__ k,
                                                        const float* __restrict__ v,
                                                        float* __restrict__ ao) {
    __shared__ __align__(16) short Ks[64][72];      // [key][dim] bf16
    __shared__ __align__(16) short Vt[64][72];      // [dim][key] bf16 (transposed)
    __shared__ __align__(16) short Ps[4][16][72];   // per-wave P tile [row][key]
    const int wid = threadIdx.x >> 6, lane = threadIdx.x & 63;
    const int lo = lane & 15, hi = lane >> 4;
    const int head = blockIdx.x >> 5;
    const int qi = blockIdx.x & 31;
    const int q0 = (31 - qi) * 64;                  // reverse: long rows first
    const int kvh = head >> 2;

    // Q fragments held in registers for the whole kernel
    bf16x8 qf[2];
    {
        const float* qr = q + (size_t)(q0 + wid*16 + lo) * HID + head*HD;
        #pragma unroll
        for (int kk = 0; kk < 2; ++kk)
            #pragma unroll
            for (int i = 0; i < 8; ++i)
                qf[kk][i] = f2b(qr[kk*32 + hi*8 + i]);
    }

    f32x4 acc[4];
    float m[4], l[4];
    #pragma unroll
    for (int r = 0; r < 4; ++r) {
        m[r] = -1e30f; l[r] = 0.f;
        acc[0][r] = 0.f; acc[1][r] = 0.f; acc[2][r] = 0.f; acc[3][r] = 0.f;
    }

    const int ntiles = q0/64 + 1;
    const int skey = threadIdx.x >> 2;        // 0..63
    const int sdg  = (threadIdx.x & 3) * 16;  // dim group base

    for (int t = 0; t < ntiles; ++t) {
        const int k0 = t * 64;
        __syncthreads();   // previous tile's LDS reads complete
        // ---- stage K (row-major bf16) and V (transposed bf16) ----
        {
            const float* kr = k + (size_t)(k0 + skey)*(KVH*HD) + kvh*HD + sdg;
            float4 a0 = ((const float4*)kr)[0], a1 = ((const float4*)kr)[1],
                   a2 = ((const float4*)kr)[2], a3 = ((const float4*)kr)[3];
            bf16x8 w0, w1;
            w0[0]=f2b(a0.x); w0[1]=f2b(a0.y); w0[2]=f2b(a0.z); w0[3]=f2b(a0.w);
            w0[4]=f2b(a1.x); w0[5]=f2b(a1.y); w0[6]=f2b(a1.z); w0[7]=f2b(a1.w);
            w1[0]=f2b(a2.x); w1[1]=f2b(a2.y); w1[2]=f2b(a2.z); w1[3]=f2b(a2.w);
            w1[4]=f2b(a3.x); w1[5]=f2b(a3.y); w1[6]=f2b(a3.z); w1[7]=f2b(a3.w);
            *(bf16x8*)&Ks[skey][sdg]     = w0;
            *(bf16x8*)&Ks[skey][sdg + 8] = w1;
            const float* vr = v + (size_t)(k0 + skey)*(KVH*HD) + kvh*HD + sdg;
            float4 b0 = ((const float4*)vr)[0], b1 = ((const float4*)vr)[1],
                   b2 = ((const float4*)vr)[2], b3 = ((const float4*)vr)[3];
            Vt[sdg+ 0][skey]=f2b(b0.x); Vt[sdg+ 1][skey]=f2b(b0.y);
            Vt[sdg+ 2][skey]=f2b(b0.z); Vt[sdg+ 3][skey]=f2b(b0.w);
            Vt[sdg+ 4][skey]=f2b(b1.x); Vt[sdg+ 5][skey]=f2b(b1.y);
            Vt[sdg+ 6][skey]=f2b(b1.z); Vt[sdg+ 7][skey]=f2b(b1.w);
            Vt[sdg+ 8][skey]=f2b(b2.x); Vt[sdg+ 9][skey]=f2b(b2.y);
            Vt[sdg+10][skey]=f2b(b2.z); Vt[sdg+11][skey]=f2b(b2.w);
            Vt[sdg+12][skey]=f2b(b3.x); Vt[sdg+13][skey]=f2b(b3.y);
            Vt[sdg+14][skey]=f2b(b3.z); Vt[sdg+15][skey]=f2b(b3.w);
        }
        __syncthreads();
        // ---- S = Q @ K^T (16 rows x 64 keys per wave) ----
        f32x4 s[4];
        #pragma unroll
        for (int f = 0; f < 4; ++f) {
            f32x4 sf; sf[0]=0.f; sf[1]=0.f; sf[2]=0.f; sf[3]=0.f;
            bf16x8 bk0 = *(const bf16x8*)&Ks[f*16 + lo][hi*8];
            sf = __builtin_amdgcn_mfma_f32_16x16x32_bf16(qf[0], bk0, sf, 0, 0, 0);
            bf16x8 bk1 = *(const bf16x8*)&Ks[f*16 + lo][32 + hi*8];
            sf = __builtin_amdgcn_mfma_f32_16x16x32_bf16(qf[1], bk1, sf, 0, 0, 0);
            s[f] = sf;
        }
        #pragma unroll
        for (int f = 0; f < 4; ++f)
            #pragma unroll
            for (int r = 0; r < 4; ++r) s[f][r] *= 0.125f;
        if (t == ntiles - 1) {   // diagonal tile: causal mask
            int qrow = q0 + wid*16 + hi*4;
            #pragma unroll
            for (int f = 0; f < 4; ++f)
                #pragma unroll
                for (int r = 0; r < 4; ++r)
                    if (k0 + f*16 + lo > qrow + r) s[f][r] = -1e30f;
        }
        // ---- online softmax (rows live across the 16-lane group) ----
        float sc_[4];
        #pragma unroll
        for (int r = 0; r < 4; ++r) {
            float x = fmaxf(fmaxf(s[0][r], s[1][r]), fmaxf(s[2][r], s[3][r]));
            x = fmaxf(x, __shfl_xor(x, 1));
            x = fmaxf(x, __shfl_xor(x, 2));
            x = fmaxf(x, __shfl_xor(x, 4));
            x = fmaxf(x, __shfl_xor(x, 8));
            float mn = fmaxf(m[r], x);
            sc_[r] = __expf(m[r] - mn);
            m[r] = mn;
            l[r] *= sc_[r];
            acc[0][r] *= sc_[r]; acc[1][r] *= sc_[r];
            acc[2][r] *= sc_[r]; acc[3][r] *= sc_[r];
        }
        float rs[4] = {0.f, 0.f, 0.f, 0.f};
        #pragma unroll
        for (int f = 0; f < 4; ++f)
            #pragma unroll
            for (int r = 0; r < 4; ++r) {
                float e = __expf(s[f][r] - m[r]);
                rs[r] += e;
                Ps[wid][hi*4 + r][f*16 + lo] = f2b(e);
            }
        #pragma unroll
        for (int r = 0; r < 4; ++r) {
            float x = rs[r];
            x += __shfl_xor(x, 1); x += __shfl_xor(x, 2);
            x += __shfl_xor(x, 4); x += __shfl_xor(x, 8);
            l[r] += x;
        }
        // P writes (cross-lane within wave) must land before A-frag reads
        asm volatile("s_waitcnt lgkmcnt(0)" ::: "memory");
        __builtin_amdgcn_sched_barrier(0);
        // ---- O += P @ V ----
        bf16x8 pa0 = *(const bf16x8*)&Ps[wid][lo][hi*8];
        bf16x8 pa1 = *(const bf16x8*)&Ps[wid][lo][32 + hi*8];
        #pragma unroll
        for (int f = 0; f < 4; ++f) {
            f32x4 o = acc[f];
            bf16x8 v0 = *(const bf16x8*)&Vt[f*16 + lo][hi*8];
            o = __builtin_amdgcn_mfma_f32_16x16x32_bf16(pa0, v0, o, 0, 0, 0);
            bf16x8 v1 = *(const bf16x8*)&Vt[f*16 + lo][32 + hi*8];
            o = __builtin_amdgcn_mfma_f32_16x16x32_bf16(pa1, v1, o, 0, 0, 0);
            acc[f] = o;
        }
    }
    #pragma unroll
    for (int r = 0; r < 4; ++r) {
        float inv = 1.0f / l[r];
        #pragma unroll
        for (int f = 0; f < 4; ++f)
            ao[(size_t)(q0 + wid*16 + hi*4 + r) * HID + head*HD + f*16 + lo] = acc[f][r] * inv;
    }
}

// ---------------- gate + top-2 routing ----------------
__global__ __launch_bounds__(64) void gate_topk_kernel(const float* __restrict__ xn,
                                                       const float* __restrict__ gw,
                                                       int* __restrict__ cnt,
                                                       int* __restrict__ idx,
                                                       float* __restrict__ wt) {
    int t = blockIdx.x, lane = threadIdx.x;
    float acc[NE] = {};
    for (int i = lane; i < HID; i += 64) {
        float x = xn[(size_t)t * HID + i];
        #pragma unroll
        for (int e = 0; e < NE; ++e) acc[e] += x * gw[e * HID + i];
    }
    #pragma unroll
    for (int e = 0; e < NE; ++e)
        for (int off = 32; off; off >>= 1) acc[e] += __shfl_xor(acc[e], off);
    if (lane == 0) {
        float mx = acc[0];
        #pragma unroll
        for (int e = 1; e < NE; ++e) mx = fmaxf(mx, acc[e]);
        float p[NE];
        #pragma unroll
        for (int e = 0; e < NE; ++e) p[e] = __expf(acc[e] - mx);
        int i0 = 0;
        #pragma unroll
        for (int e = 1; e < NE; ++e) if (p[e] > p[i0]) i0 = e;
        int i1 = -1;
        #pragma unroll
        for (int e = 0; e < NE; ++e) if (e != i0 && (i1 < 0 || p[e] > p[i1])) i1 = e;
        float w0 = p[i0], w1 = p[i1];
        float inv = 1.0f / (w0 + w1);
        int s0 = atomicAdd(&cnt[i0], 1);
        idx[i0 * S_LEN + s0] = t; wt[i0 * S_LEN + s0] = w0 * inv;
        int s1 = atomicAdd(&cnt[i1], 1);
        idx[i1 * S_LEN + s1] = t; wt[i1 * S_LEN + s1] = w1 * inv;
    }
}

// ---------------- MoE mlp1: a = silu(x@w1^T) * (x@w3^T), gathered rows ----------------
__global__ __launch_bounds__(256) void moe_mlp1_kernel(const float* __restrict__ X,
                                                       const float* __restrict__ W1,
                                                       const float* __restrict__ W3,
                                                       const int* __restrict__ cnt,
                                                       const int* __restrict__ idx,
                                                       float* __restrict__ abuf) {
    int e = blockIdx.z;
    int ne = cnt[e];
    int m0 = blockIdx.y * 64;
    if (m0 >= ne) return;
    int f0 = blockIdx.x * 64;
    __shared__ float As[16][65], B1s[16][65], B3s[16][65];
    __shared__ int rows[64];
    int tid = threadIdx.x;
    if (tid < 64) {
        int slot = m0 + tid;
        rows[tid] = (slot < ne) ? idx[e * S_LEN + slot] : 0;
    }
    __syncthreads();
    const float* w1e = W1 + (size_t)e * FF * HID;
    const float* w3e = W3 + (size_t)e * FF * HID;
    int lr = tid >> 2;
    int lc = (tid & 3) << 2;
    int ty = tid >> 4, tx = tid & 15;
    int arow = rows[lr];
    float accg[4][4] = {}, accu[4][4] = {};
    for (int k0 = 0; k0 < HID; k0 += 16) {
        float4 av  = *(const float4*)(X   + (size_t)arow * HID + k0 + lc);
        float4 b1v = *(const float4*)(w1e + (size_t)(f0 + lr) * HID + k0 + lc);
        float4 b3v = *(const float4*)(w3e + (size_t)(f0 + lr) * HID + k0 + lc);
        __syncthreads();
        As[lc+0][lr]  = av.x;  As[lc+1][lr]  = av.y;  As[lc+2][lr]  = av.z;  As[lc+3][lr]  = av.w;
        B1s[lc+0][lr] = b1v.x; B1s[lc+1][lr] = b1v.y; B1s[lc+2][lr] = b1v.z; B1s[lc+3][lr] = b1v.w;
        B3s[lc+0][lr] = b3v.x; B3s[lc+1][lr] = b3v.y; B3s[lc+2][lr] = b3v.z; B3s[lc+3][lr] = b3v.w;
        __syncthreads();
        #pragma unroll
        for (int kk = 0; kk < 16; ++kk) {
            float a0 = As[kk][ty*4+0], a1 = As[kk][ty*4+1], a2 = As[kk][ty*4+2], a3 = As[kk][ty*4+3];
            float g0 = B1s[kk][tx*4+0], g1 = B1s[kk][tx*4+1], g2 = B1s[kk][tx*4+2], g3 = B1s[kk][tx*4+3];
            float u0 = B3s[kk][tx*4+0], u1 = B3s[kk][tx*4+1], u2 = B3s[kk][tx*4+2], u3 = B3s[kk][tx*4+3];
            accg[0][0]+=a0*g0; accg[0][1]+=a0*g1; accg[0][2]+=a0*g2; accg[0][3]+=a0*g3;
            accg[1][0]+=a1*g0; accg[1][1]+=a1*g1; accg[1][2]+=a1*g2; accg[1][3]+=a1*g3;
            accg[2][0]+=a2*g0; accg[2][1]+=a2*g1; accg[2][2]+=a2*g2; accg[2][3]+=a2*g3;
            accg[3][0]+=a3*g0; accg[3][1]+=a3*g1; accg[3][2]+=a3*g2; accg[3][3]+=a3*g3;
            accu[0][0]+=a0*u0; accu[0][1]+=a0*u1; accu[0][2]+=a0*u2; accu[0][3]+=a0*u3;
            accu[1][0]+=a1*u0; accu[1][1]+=a1*u1; accu[1][2]+=a1*u2; accu[1][3]+=a1*u3;
            accu[2][0]+=a2*u0; accu[2][1]+=a2*u1; accu[2][2]+=a2*u2; accu[2][3]+=a2*u3;
            accu[3][0]+=a3*u0; accu[3][1]+=a3*u1; accu[3][2]+=a3*u2; accu[3][3]+=a3*u3;
        }
    }
    #pragma unroll
    for (int i = 0; i < 4; ++i) {
        int slot = m0 + ty*4 + i;
        if (slot >= ne) continue;
        #pragma unroll
        for (int j = 0; j < 4; ++j) {
            float g = accg[i][j], u = accu[i][j];
            float a = g * (1.0f / (1.0f + __expf(-g))) * u;
            abuf[(size_t)e * S_LEN * FF + (size_t)slot * FF + f0 + tx*4 + j] = a;
        }
    }
}

// ---------------- MoE mlp2: h += wt * (a @ w2^T) ----------------
__global__ __launch_bounds__(256) void moe_mlp2_kernel(const float* __restrict__ abuf,
                                                       const float* __restrict__ W2,
                                                       const int* __restrict__ cnt,
                                                       const int* __restrict__ idx,
                                                       const float* __restrict__ wt,
                                                       float* __restrict__ hbuf) {
    int e = blockIdx.z;
    int ne = cnt[e];
    int m0 = blockIdx.y * 64;
    if (m0 >= ne) return;
    int n0 = blockIdx.x * 64;
    __shared__ float As[16][65], Bs[16][65];
    const float* Ae = abuf + (size_t)e * S_LEN * FF;
    const float* w2e = W2 + (size_t)e * HID * FF;
    int tid = threadIdx.x;
    int lr = tid >> 2;
    int lc = (tid & 3) << 2;
    int ty = tid >> 4, tx = tid & 15;
    float acc[4][4] = {};
    for (int k0 = 0; k0 < FF; k0 += 16) {
        float4 av = *(const float4*)(Ae  + (size_t)(m0 + lr) * FF + k0 + lc);
        float4 bv = *(const float4*)(w2e + (size_t)(n0 + lr) * FF + k0 + lc);
        __syncthreads();
        As[lc+0][lr] = av.x; As[lc+1][lr] = av.y; As[lc+2][lr] = av.z; As[lc+3][lr] = av.w;
        Bs[lc+0][lr] = bv.x; Bs[lc+1][lr] = bv.y; Bs[lc+2][lr] = bv.z; Bs[lc+3][lr] = bv.w;
        __syncthreads();
        #pragma unroll
        for (int kk = 0; kk < 16; ++kk) {
            float a0 = As[kk][ty*4+0], a1 = As[kk][ty*4+1], a2 = As[kk][ty*4+2], a3 = As[kk][ty*4+3];
            float b0 = Bs[kk][tx*4+0], b1 = Bs[kk][tx*4+1], b2 = Bs[kk][tx*4+2], b3 = Bs[kk][tx*4+3];
            acc[0][0] += a0*b0; acc[0][1] += a0*b1; acc[0][2] += a0*b2; acc[0][3] += a0*b3;
            acc[1][0] += a1*b0; acc[1][1] += a1*b1; acc[1][2] += a1*b2; acc[1][3] += a1*b3;
            acc[2][0] += a2*b0; acc[2][1] += a2*b1; acc[2][2] += a2*b2; acc[2][3] += a2*b3;
            acc[3][0] += a3*b0; acc[3][1] += a3*b1; acc[3][2] += a3*b2; acc[3][3] += a3*b3;
        }
    }
    #pragma unroll
    for (int i = 0; i < 4; ++i) {
        int slot = m0 + ty*4 + i;
        if (slot >= ne) continue;
        int tok = idx[e * S_LEN + slot];
        float wv = wt[e * S_LEN + slot];
        #pragma unroll
        for (int j = 0; j < 4; ++j) {
            atomicAdd(&hbuf[(size_t)tok * HID + n0 + tx*4 + j], acc[i][j] * wv);
        }
    }
}

extern "C" void kernel_launch(void* const* d_in, const int* in_sizes, int n_in,
                              void* d_out, int out_size, void* d_ws, size_t ws_size,
                              hipStream_t stream) {
    const float* emb = (const float*)d_in[0];
    const float* ln1 = (const float*)d_in[1];
    const float* ln2 = (const float*)d_in[2];
    const float* fln = (const float*)d_in[3];
    const float* qw  = (const float*)d_in[4];
    const float* kw  = (const float*)d_in[5];
    const float* vw  = (const float*)d_in[6];
    const float* ow  = (const float*)d_in[7];
    const float* gw  = (const float*)d_in[8];
    const float* w1  = (const float*)d_in[9];
    const float* w2  = (const float*)d_in[10];
    const float* w3  = (const float*)d_in[11];

    float* ws   = (float*)d_ws;
    float* h    = ws + OFF_H;
    float* xn   = ws + OFF_XN;
    float* q    = ws + OFF_Q;
    float* kb   = ws + OFF_K;
    float* vb   = ws + OFF_V;
    float* ao   = ws + OFF_AO;
    float* cosb = ws + OFF_COS;
    float* sinb = ws + OFF_SIN;
    float* wt   = ws + OFF_WT;
    float* abuf = ws + OFF_ABUF;
    int*   cnt  = (int*)(ws + OFF_INT);
    int*   idx  = cnt + 8;

    hipMemcpyAsync(h, emb, (size_t)S_LEN * HID * sizeof(float), hipMemcpyDeviceToDevice, stream);
    rope_tables_kernel<<<S_LEN * 32 / 256, 256, 0, stream>>>(cosb, sinb);

    for (int l = 0; l < NL; ++l) {
        rmsnorm_kernel<<<S_LEN, 256, 0, stream>>>(h, ln1 + l * HID, xn);
        gemm_nt_kernel<<<dim3(16, 32), 256, 0, stream>>>(xn, qw + (size_t)l * HID * HID, q, nullptr, HID, HID);
        gemm_nt_kernel<<<dim3(4, 32), 256, 0, stream>>>(xn, kw + (size_t)l * KVH * HD * HID, kb, nullptr, KVH * HD, HID);
        gemm_nt_kernel<<<dim3(4, 32), 256, 0, stream>>>(xn, vw + (size_t)l * KVH * HD * HID, vb, nullptr, KVH * HD, HID);
        rope_apply_kernel<<<(S_LEN * NHEAD * 32) / 256, 256, 0, stream>>>(q, cosb, sinb, NHEAD, S_LEN * NHEAD * 32);
        rope_apply_kernel<<<(S_LEN * KVH * 32) / 256, 256, 0, stream>>>(kb, cosb, sinb, KVH, S_LEN * KVH * 32);
        attn_mfma_kernel<<<NHEAD * 32, 256, 0, stream>>>(q, kb, vb, ao);
        gemm_nt_kernel<<<dim3(16, 32), 256, 0, stream>>>(ao, ow + (size_t)l * HID * HID, h, h, HID, HID);
        rmsnorm_kernel<<<S_LEN, 256, 0, stream>>>(h, ln2 + l * HID, xn);
        hipMemsetAsync(cnt, 0, 8 * sizeof(int), stream);
        gate_topk_kernel<<<S_LEN, 64, 0, stream>>>(xn, gw + (size_t)l * NE * HID, cnt, idx, wt);
        moe_mlp1_kernel<<<dim3(16, 32, 8), 256, 0, stream>>>(xn, w1 + (size_t)l * NE * FF * HID,
                                                             w3 + (size_t)l * NE * FF * HID, cnt, idx, abuf);
        moe_mlp2_kernel<<<dim3(16, 32, 8), 256, 0, stream>>>(abuf, w2 + (size_t)l * NE * HID * FF, cnt, idx, wt, h);
    }
    rmsnorm_kernel<<<S_LEN, 256, 0, stream>>>(h, fln, (float*)d_out);
}

// Round 4
// 1091.646 us; speedup vs baseline: 4.1916x; 1.9637x over previous
//
#include <hip/hip_runtime.h>
#include <hip/hip_bf16.h>
#include <math.h>

#define S_LEN 2048
#define HID   1024
#define NHEAD 16
#define KVH   4
#define HD    64
#define FF    1024
#define NE    8
#define NL    2

// ---- workspace layout (float offsets) ----
#define OFF_H    0
#define OFF_XN   (OFF_H    + S_LEN*HID)
#define OFF_Q    (OFF_XN   + S_LEN*HID)
#define OFF_K    (OFF_Q    + S_LEN*HID)
#define OFF_V    (OFF_K    + S_LEN*KVH*HD)
#define OFF_AO   (OFF_V    + S_LEN*KVH*HD)
#define OFF_COS  (OFF_AO   + S_LEN*HID)
#define OFF_SIN  (OFF_COS  + S_LEN*32)
#define OFF_WT   (OFF_SIN  + S_LEN*32)
#define OFF_ABUF (OFF_WT   + NE*S_LEN)
#define OFF_INT  (OFF_ABUF + NE*S_LEN*FF)

typedef __attribute__((ext_vector_type(8))) short bf16x8;
typedef __attribute__((ext_vector_type(4))) float f32x4;

__device__ __forceinline__ short f2b(float f) {
    union { __hip_bfloat16 b; short s; } u;
    u.b = __float2bfloat16(f);
    return u.s;
}

__device__ __forceinline__ bf16x8 pack8(float4 a, float4 b) {
    bf16x8 w;
    w[0]=f2b(a.x); w[1]=f2b(a.y); w[2]=f2b(a.z); w[3]=f2b(a.w);
    w[4]=f2b(b.x); w[5]=f2b(b.y); w[6]=f2b(b.z); w[7]=f2b(b.w);
    return w;
}

// split fp32 -> hi (top-16-bit truncation) + lo (bf16 of remainder); hi+lo ~ 2^-17 rel
__device__ __forceinline__ void split8(const float* v, bf16x8& h8, bf16x8& l8) {
    #pragma unroll
    for (int i = 0; i < 8; ++i) {
        union { float f; unsigned u; } a; a.f = v[i];
        h8[i] = (short)(a.u >> 16);
        union { float f; unsigned u; } r; r.u = a.u & 0xFFFF0000u;
        l8[i] = f2b(v[i] - r.f);
    }
}

__device__ __forceinline__ void split_pair(float4 a, float4 b, bf16x8& h8, bf16x8& l8) {
    float v[8] = {a.x, a.y, a.z, a.w, b.x, b.y, b.z, b.w};
    split8(v, h8, l8);
}

// ---------------- RoPE tables ----------------
__global__ void rope_tables_kernel(float* __restrict__ cosb, float* __restrict__ sinb) {
    int gid = blockIdx.x * 256 + threadIdx.x;     // S_LEN*32 total
    int t = gid >> 5, i = gid & 31;
    float invf = powf(1.0e6f, -(float)i / 32.0f);
    float ang = (float)t * invf;
    cosb[gid] = cosf(ang);
    sinb[gid] = sinf(ang);
}

// ---------------- RMSNorm ----------------
__global__ __launch_bounds__(256) void rmsnorm_kernel(const float* __restrict__ x,
                                                      const float* __restrict__ w,
                                                      float* __restrict__ out) {
    int row = blockIdx.x;
    const float4* xr = (const float4*)(x + (size_t)row * HID);
    float4 xv = xr[threadIdx.x];
    float ss = xv.x*xv.x + xv.y*xv.y + xv.z*xv.z + xv.w*xv.w;
    for (int off = 32; off; off >>= 1) ss += __shfl_xor(ss, off);
    __shared__ float sred[4];
    if ((threadIdx.x & 63) == 0) sred[threadIdx.x >> 6] = ss;
    __syncthreads();
    float tot = sred[0] + sred[1] + sred[2] + sred[3];
    float scale = rsqrtf(tot * (1.0f / (float)HID) + 1e-5f);
    float4 wv = ((const float4*)w)[threadIdx.x];
    float4 o;
    o.x = xv.x * scale * wv.x; o.y = xv.y * scale * wv.y;
    o.z = xv.z * scale * wv.z; o.w = xv.w * scale * wv.w;
    ((float4*)(out + (size_t)row * HID))[threadIdx.x] = o;
}

// ---------------- RoPE apply (in-place, q or k) ----------------
__global__ void rope_apply_kernel(float* __restrict__ p, const float* __restrict__ cosb,
                                  const float* __restrict__ sinb, int nh, int total) {
    int gid = blockIdx.x * 256 + threadIdx.x;
    if (gid >= total) return;
    int per = nh * 32;
    int t = gid / per, r = gid % per;
    int hh = r >> 5, i = r & 31;
    float c = cosb[t*32 + i], s = sinb[t*32 + i];
    float* base = p + (size_t)t * (nh * HD) + hh * HD + i;
    float a = base[0], b = base[32];
    base[0]  = a * c - b * s;
    base[32] = b * c + a * s;
}

// ---------------- split-bf16 MFMA GEMM: C = A[M,K] @ B[N,K]^T (+resid), ~fp32 accurate ----
// 128x128 tile, 4 waves (2x2) each 64x64. 3 products: Ah*Bh + Al*Bh + Ah*Bl.
__global__ __launch_bounds__(256) void gemm3_mfma_kernel(const float* __restrict__ A,
                                                         const float* __restrict__ B,
                                                         float* __restrict__ C,
                                                         const float* __restrict__ resid,
                                                         int N, int Kd) {
    __shared__ __align__(16) short Ah[128*40];
    __shared__ __align__(16) short Al[128*40];
    __shared__ __align__(16) short Bh[128*40];
    __shared__ __align__(16) short Bl[128*40];
    const int tid = threadIdx.x;
    const int wid = tid >> 6, lane = tid & 63;
    const int lo = lane & 15, hi = lane >> 4;
    const int wr = wid >> 1, wc = wid & 1;
    const int m0 = blockIdx.y * 128, n0 = blockIdx.x * 128;
    const int arow = tid >> 2;
    const int apart = (tid & 3) * 8;
    const float* Ap0 = A + (size_t)(m0 + arow) * Kd + apart;
    const float* Ap1 = A + (size_t)(m0 + 64 + arow) * Kd + apart;
    const float* Bp0 = B + (size_t)(n0 + arow) * Kd + apart;
    const float* Bp1 = B + (size_t)(n0 + 64 + arow) * Kd + apart;

    f32x4 acc[4][4];
    #pragma unroll
    for (int m = 0; m < 4; ++m)
        #pragma unroll
        for (int n = 0; n < 4; ++n) { acc[m][n][0]=0.f; acc[m][n][1]=0.f; acc[m][n][2]=0.f; acc[m][n][3]=0.f; }

    for (int k0 = 0; k0 < Kd; k0 += 32) {
        float4 a0 = ((const float4*)(Ap0 + k0))[0], a1 = ((const float4*)(Ap0 + k0))[1];
        float4 a2 = ((const float4*)(Ap1 + k0))[0], a3 = ((const float4*)(Ap1 + k0))[1];
        float4 b0 = ((const float4*)(Bp0 + k0))[0], b1 = ((const float4*)(Bp0 + k0))[1];
        float4 b2 = ((const float4*)(Bp1 + k0))[0], b3 = ((const float4*)(Bp1 + k0))[1];
        bf16x8 h8, l8;
        __syncthreads();
        split_pair(a0, a1, h8, l8);
        *(bf16x8*)&Ah[arow*40 + apart] = h8;       *(bf16x8*)&Al[arow*40 + apart] = l8;
        split_pair(a2, a3, h8, l8);
        *(bf16x8*)&Ah[(64+arow)*40 + apart] = h8;  *(bf16x8*)&Al[(64+arow)*40 + apart] = l8;
        split_pair(b0, b1, h8, l8);
        *(bf16x8*)&Bh[arow*40 + apart] = h8;       *(bf16x8*)&Bl[arow*40 + apart] = l8;
        split_pair(b2, b3, h8, l8);
        *(bf16x8*)&Bh[(64+arow)*40 + apart] = h8;  *(bf16x8*)&Bl[(64+arow)*40 + apart] = l8;
        __syncthreads();
        bf16x8 ah[4], al[4], bh[4], bl[4];
        #pragma unroll
        for (int m = 0; m < 4; ++m) {
            ah[m] = *(const bf16x8*)&Ah[(wr*64 + m*16 + lo)*40 + hi*8];
            al[m] = *(const bf16x8*)&Al[(wr*64 + m*16 + lo)*40 + hi*8];
        }
        #pragma unroll
        for (int n = 0; n < 4; ++n) {
            bh[n] = *(const bf16x8*)&Bh[(wc*64 + n*16 + lo)*40 + hi*8];
            bl[n] = *(const bf16x8*)&Bl[(wc*64 + n*16 + lo)*40 + hi*8];
        }
        #pragma unroll
        for (int m = 0; m < 4; ++m)
            #pragma unroll
            for (int n = 0; n < 4; ++n) {
                acc[m][n] = __builtin_amdgcn_mfma_f32_16x16x32_bf16(ah[m], bh[n], acc[m][n], 0, 0, 0);
                acc[m][n] = __builtin_amdgcn_mfma_f32_16x16x32_bf16(al[m], bh[n], acc[m][n], 0, 0, 0);
                acc[m][n] = __builtin_amdgcn_mfma_f32_16x16x32_bf16(ah[m], bl[n], acc[m][n], 0, 0, 0);
            }
    }
    #pragma unroll
    for (int m = 0; m < 4; ++m)
        #pragma unroll
        for (int n = 0; n < 4; ++n)
            #pragma unroll
            for (int r = 0; r < 4; ++r) {
                int row = m0 + wr*64 + m*16 + hi*4 + r;
                int col = n0 + wc*64 + n*16 + lo;
                float val = acc[m][n][r];
                if (resid) val += resid[(size_t)row * N + col];
                C[(size_t)row * N + col] = val;
            }
}

// ---------------- MFMA flash attention (round-2 verified) ----------------
__global__ __launch_bounds__(256) void attn_mfma_kernel(const float* __restrict__ q,
                                                        const float* __restrict__ k,
                                                        const float* __restrict__ v,
                                                        float* __restrict__ ao) {
    __shared__ __align__(16) short Ks[64][72];
    __shared__ __align__(16) short Vt[64][72];
    __shared__ __align__(16) short Ps[4][16][72];
    const int wid = threadIdx.x >> 6, lane = threadIdx.x & 63;
    const int lo = lane & 15, hi = lane >> 4;
    const int head = blockIdx.x >> 5;
    const int qi = blockIdx.x & 31;
    const int q0 = (31 - qi) * 64;
    const int kvh = head >> 2;

    bf16x8 qf[2];
    {
        const float* qr = q + (size_t)(q0 + wid*16 + lo) * HID + head*HD;
        #pragma unroll
        for (int kk = 0; kk < 2; ++kk)
            #pragma unroll
            for (int i = 0; i < 8; ++i)
                qf[kk][i] = f2b(qr[kk*32 + hi*8 + i]);
    }

    f32x4 acc[4];
    float m[4], l[4];
    #pragma unroll
    for (int r = 0; r < 4; ++r) {
        m[r] = -1e30f; l[r] = 0.f;
        acc[0][r] = 0.f; acc[1][r] = 0.f; acc[2][r] = 0.f; acc[3][r] = 0.f;
    }

    const int ntiles = q0/64 + 1;
    const int skey = threadIdx.x >> 2;
    const int sdg  = (threadIdx.x & 3) * 16;

    for (int t = 0; t < ntiles; ++t) {
        const int k0 = t * 64;
        __syncthreads();
        {
            const float* kr = k + (size_t)(k0 + skey)*(KVH*HD) + kvh*HD + sdg;
            float4 a0 = ((const float4*)kr)[0], a1 = ((const float4*)kr)[1],
                   a2 = ((const float4*)kr)[2], a3 = ((const float4*)kr)[3];
            *(bf16x8*)&Ks[skey][sdg]     = pack8(a0, a1);
            *(bf16x8*)&Ks[skey][sdg + 8] = pack8(a2, a3);
            const float* vr = v + (size_t)(k0 + skey)*(KVH*HD) + kvh*HD + sdg;
            float4 b0 = ((const float4*)vr)[0], b1 = ((const float4*)vr)[1],
                   b2 = ((const float4*)vr)[2], b3 = ((const float4*)vr)[3];
            Vt[sdg+ 0][skey]=f2b(b0.x); Vt[sdg+ 1][skey]=f2b(b0.y);
            Vt[sdg+ 2][skey]=f2b(b0.z); Vt[sdg+ 3][skey]=f2b(b0.w);
            Vt[sdg+ 4][skey]=f2b(b1.x); Vt[sdg+ 5][skey]=f2b(b1.y);
            Vt[sdg+ 6][skey]=f2b(b1.z); Vt[sdg+ 7][skey]=f2b(b1.w);
            Vt[sdg+ 8][skey]=f2b(b2.x); Vt[sdg+ 9][skey]=f2b(b2.y);
            Vt[sdg+10][skey]=f2b(b2.z); Vt[sdg+11][skey]=f2b(b2.w);
            Vt[sdg+12][skey]=f2b(b3.x); Vt[sdg+13][skey]=f2b(b3.y);
            Vt[sdg+14][skey]=f2b(b3.z); Vt[sdg+15][skey]=f2b(b3.w);
        }
        __syncthreads();
        f32x4 s[4];
        #pragma unroll
        for (int f = 0; f < 4; ++f) {
            f32x4 sf; sf[0]=0.f; sf[1]=0.f; sf[2]=0.f; sf[3]=0.f;
            bf16x8 bk0 = *(const bf16x8*)&Ks[f*16 + lo][hi*8];
            sf = __builtin_amdgcn_mfma_f32_16x16x32_bf16(qf[0], bk0, sf, 0, 0, 0);
            bf16x8 bk1 = *(const bf16x8*)&Ks[f*16 + lo][32 + hi*8];
            sf = __builtin_amdgcn_mfma_f32_16x16x32_bf16(qf[1], bk1, sf, 0, 0, 0);
            s[f] = sf;
        }
        #pragma unroll
        for (int f = 0; f < 4; ++f)
            #pragma unroll
            for (int r = 0; r < 4; ++r) s[f][r] *= 0.125f;
        if (t == ntiles - 1) {
            int qrow = q0 + wid*16 + hi*4;
            #pragma unroll
            for (int f = 0; f < 4; ++f)
                #pragma unroll
                for (int r = 0; r < 4; ++r)
                    if (k0 + f*16 + lo > qrow + r) s[f][r] = -1e30f;
        }
        float sc_[4];
        #pragma unroll
        for (int r = 0; r < 4; ++r) {
            float x = fmaxf(fmaxf(s[0][r], s[1][r]), fmaxf(s[2][r], s[3][r]));
            x = fmaxf(x, __shfl_xor(x, 1));
            x = fmaxf(x, __shfl_xor(x, 2));
            x = fmaxf(x, __shfl_xor(x, 4));
            x = fmaxf(x, __shfl_xor(x, 8));
            float mn = fmaxf(m[r], x);
            sc_[r] = __expf(m[r] - mn);
            m[r] = mn;
            l[r] *= sc_[r];
            acc[0][r] *= sc_[r]; acc[1][r] *= sc_[r];
            acc[2][r] *= sc_[r]; acc[3][r] *= sc_[r];
        }
        float rs[4] = {0.f, 0.f, 0.f, 0.f};
        #pragma unroll
        for (int f = 0; f < 4; ++f)
            #pragma unroll
            for (int r = 0; r < 4; ++r) {
                float e = __expf(s[f][r] - m[r]);
                rs[r] += e;
                Ps[wid][hi*4 + r][f*16 + lo] = f2b(e);
            }
        #pragma unroll
        for (int r = 0; r < 4; ++r) {
            float x = rs[r];
            x += __shfl_xor(x, 1); x += __shfl_xor(x, 2);
            x += __shfl_xor(x, 4); x += __shfl_xor(x, 8);
            l[r] += x;
        }
        asm volatile("s_waitcnt lgkmcnt(0)" ::: "memory");
        __builtin_amdgcn_sched_barrier(0);
        bf16x8 pa0 = *(const bf16x8*)&Ps[wid][lo][hi*8];
        bf16x8 pa1 = *(const bf16x8*)&Ps[wid][lo][32 + hi*8];
        #pragma unroll
        for (int f = 0; f < 4; ++f) {
            f32x4 o = acc[f];
            bf16x8 v0 = *(const bf16x8*)&Vt[f*16 + lo][hi*8];
            o = __builtin_amdgcn_mfma_f32_16x16x32_bf16(pa0, v0, o, 0, 0, 0);
            bf16x8 v1 = *(const bf16x8*)&Vt[f*16 + lo][32 + hi*8];
            o = __builtin_amdgcn_mfma_f32_16x16x32_bf16(pa1, v1, o, 0, 0, 0);
            acc[f] = o;
        }
    }
    #pragma unroll
    for (int r = 0; r < 4; ++r) {
        float inv = 1.0f / l[r];
        #pragma unroll
        for (int f = 0; f < 4; ++f)
            ao[(size_t)(q0 + wid*16 + hi*4 + r) * HID + head*HD + f*16 + lo] = acc[f][r] * inv;
    }
}

// ---------------- gate + top-2 routing (exact fp32) ----------------
__global__ __launch_bounds__(64) void gate_topk_kernel(const float* __restrict__ xn,
                                                       const float* __restrict__ gw,
                                                       int* __restrict__ cnt,
                                                       int* __restrict__ idx,
                                                       float* __restrict__ wt) {
    int t = blockIdx.x, lane = threadIdx.x;
    float acc[NE] = {};
    for (int i = lane; i < HID; i += 64) {
        float x = xn[(size_t)t * HID + i];
        #pragma unroll
        for (int e = 0; e < NE; ++e) acc[e] += x * gw[e * HID + i];
    }
    #pragma unroll
    for (int e = 0; e < NE; ++e)
        for (int off = 32; off; off >>= 1) acc[e] += __shfl_xor(acc[e], off);
    if (lane == 0) {
        float mx = acc[0];
        #pragma unroll
        for (int e = 1; e < NE; ++e) mx = fmaxf(mx, acc[e]);
        float p[NE];
        #pragma unroll
        for (int e = 0; e < NE; ++e) p[e] = __expf(acc[e] - mx);
        int i0 = 0;
        #pragma unroll
        for (int e = 1; e < NE; ++e) if (p[e] > p[i0]) i0 = e;
        int i1 = -1;
        #pragma unroll
        for (int e = 0; e < NE; ++e) if (e != i0 && (i1 < 0 || p[e] > p[i1])) i1 = e;
        float w0 = p[i0], w1 = p[i1];
        float inv = 1.0f / (w0 + w1);
        int s0 = atomicAdd(&cnt[i0], 1);
        idx[i0 * S_LEN + s0] = t; wt[i0 * S_LEN + s0] = w0 * inv;
        int s1 = atomicAdd(&cnt[i1], 1);
        idx[i1 * S_LEN + s1] = t; wt[i1 * S_LEN + s1] = w1 * inv;
    }
}

// ---------------- MoE mlp1 (split MFMA): abuf = fp32( silu(x@w1^T) * (x@w3^T) ) ----------
// tile 128 rows x 64 F-cols; 4 waves 2x2 -> each 64x32.
__global__ __launch_bounds__(256) void moe_mlp1_mfma(const float* __restrict__ X,
                                                     const float* __restrict__ W1,
                                                     const float* __restrict__ W3,
                                                     const int* __restrict__ cnt,
                                                     const int* __restrict__ idx,
                                                     float* __restrict__ abuf) {
    int e = blockIdx.z;
    int ne = cnt[e];
    int m0 = blockIdx.y * 128;
    if (m0 >= ne) return;
    int f0 = blockIdx.x * 64;
    __shared__ __align__(16) short Ahs[128*40];
    __shared__ __align__(16) short Als[128*40];
    __shared__ __align__(16) short Ghs[64*40];
    __shared__ __align__(16) short Gls[64*40];
    __shared__ __align__(16) short Uhs[64*40];
    __shared__ __align__(16) short Uls[64*40];
    __shared__ int rows[128];
    const int tid = threadIdx.x;
    if (tid < 128) {
        int slot = m0 + tid;
        rows[tid] = (slot < ne) ? idx[e * S_LEN + slot] : 0;
    }
    __syncthreads();
    const int wid = tid >> 6, lane = tid & 63;
    const int lo = lane & 15, hi = lane >> 4;
    const int wr = wid >> 1, wc = wid & 1;
    const int arow = tid >> 2;
    const int apart = (tid & 3) * 8;
    const float* Ap0 = X + (size_t)rows[arow] * HID + apart;
    const float* Ap1 = X + (size_t)rows[64 + arow] * HID + apart;
    const float* B1p = W1 + (size_t)e * FF * HID + (size_t)(f0 + arow) * HID + apart;
    const float* B3p = W3 + (size_t)e * FF * HID + (size_t)(f0 + arow) * HID + apart;

    f32x4 ag[4][2], au[4][2];
    #pragma unroll
    for (int m = 0; m < 4; ++m)
        #pragma unroll
        for (int n = 0; n < 2; ++n) {
            ag[m][n][0]=0.f; ag[m][n][1]=0.f; ag[m][n][2]=0.f; ag[m][n][3]=0.f;
            au[m][n][0]=0.f; au[m][n][1]=0.f; au[m][n][2]=0.f; au[m][n][3]=0.f;
        }

    for (int k0 = 0; k0 < HID; k0 += 32) {
        float4 a0 = ((const float4*)(Ap0 + k0))[0], a1 = ((const float4*)(Ap0 + k0))[1];
        float4 a2 = ((const float4*)(Ap1 + k0))[0], a3 = ((const float4*)(Ap1 + k0))[1];
        float4 g0 = ((const float4*)(B1p + k0))[0], g1 = ((const float4*)(B1p + k0))[1];
        float4 u0 = ((const float4*)(B3p + k0))[0], u1 = ((const float4*)(B3p + k0))[1];
        bf16x8 h8, l8;
        __syncthreads();
        split_pair(a0, a1, h8, l8);
        *(bf16x8*)&Ahs[arow*40 + apart] = h8;       *(bf16x8*)&Als[arow*40 + apart] = l8;
        split_pair(a2, a3, h8, l8);
        *(bf16x8*)&Ahs[(64+arow)*40 + apart] = h8;  *(bf16x8*)&Als[(64+arow)*40 + apart] = l8;
        split_pair(g0, g1, h8, l8);
        *(bf16x8*)&Ghs[arow*40 + apart] = h8;       *(bf16x8*)&Gls[arow*40 + apart] = l8;
        split_pair(u0, u1, h8, l8);
        *(bf16x8*)&Uhs[arow*40 + apart] = h8;       *(bf16x8*)&Uls[arow*40 + apart] = l8;
        __syncthreads();
        bf16x8 ah[4], al[4], gh[2], gl[2], uh[2], ul[2];
        #pragma unroll
        for (int m = 0; m < 4; ++m) {
            ah[m] = *(const bf16x8*)&Ahs[(wr*64 + m*16 + lo)*40 + hi*8];
            al[m] = *(const bf16x8*)&Als[(wr*64 + m*16 + lo)*40 + hi*8];
        }
        #pragma unroll
        for (int n = 0; n < 2; ++n) {
            gh[n] = *(const bf16x8*)&Ghs[(wc*32 + n*16 + lo)*40 + hi*8];
            gl[n] = *(const bf16x8*)&Gls[(wc*32 + n*16 + lo)*40 + hi*8];
            uh[n] = *(const bf16x8*)&Uhs[(wc*32 + n*16 + lo)*40 + hi*8];
            ul[n] = *(const bf16x8*)&Uls[(wc*32 + n*16 + lo)*40 + hi*8];
        }
        #pragma unroll
        for (int m = 0; m < 4; ++m)
            #pragma unroll
            for (int n = 0; n < 2; ++n) {
                ag[m][n] = __builtin_amdgcn_mfma_f32_16x16x32_bf16(ah[m], gh[n], ag[m][n], 0, 0, 0);
                ag[m][n] = __builtin_amdgcn_mfma_f32_16x16x32_bf16(al[m], gh[n], ag[m][n], 0, 0, 0);
                ag[m][n] = __builtin_amdgcn_mfma_f32_16x16x32_bf16(ah[m], gl[n], ag[m][n], 0, 0, 0);
                au[m][n] = __builtin_amdgcn_mfma_f32_16x16x32_bf16(ah[m], uh[n], au[m][n], 0, 0, 0);
                au[m][n] = __builtin_amdgcn_mfma_f32_16x16x32_bf16(al[m], uh[n], au[m][n], 0, 0, 0);
                au[m][n] = __builtin_amdgcn_mfma_f32_16x16x32_bf16(ah[m], ul[n], au[m][n], 0, 0, 0);
            }
    }
    #pragma unroll
    for (int m = 0; m < 4; ++m)
        #pragma unroll
        for (int n = 0; n < 2; ++n)
            #pragma unroll
            for (int r = 0; r < 4; ++r) {
                int slot = m0 + wr*64 + m*16 + hi*4 + r;
                if (slot >= ne) continue;
                float g = ag[m][n][r], u = au[m][n][r];
                float a = g * (1.0f / (1.0f + __expf(-g))) * u;
                abuf[((size_t)e * S_LEN + slot) * FF + f0 + wc*32 + n*16 + lo] = a;
            }
}

// ---------------- MoE mlp2 (split MFMA): h += wt * (a @ w2^T) ----------------
__global__ __launch_bounds__(256) void moe_mlp2_mfma(const float* __restrict__ abuf,
                                                     const float* __restrict__ W2,
                                                     const int* __restrict__ cnt,
                                                     const int* __restrict__ idx,
                                                     const float* __restrict__ wt,
                                                     float* __restrict__ hbuf) {
    int e = blockIdx.z;
    int ne = cnt[e];
    int m0 = blockIdx.y * 128;
    if (m0 >= ne) return;
    int n0 = blockIdx.x * 128;
    __shared__ __align__(16) short Ah[128*40];
    __shared__ __align__(16) short Al[128*40];
    __shared__ __align__(16) short Bh[128*40];
    __shared__ __align__(16) short Bl[128*40];
    const int tid = threadIdx.x;
    const int wid = tid >> 6, lane = tid & 63;
    const int lo = lane & 15, hi = lane >> 4;
    const int wr = wid >> 1, wc = wid & 1;
    const int arow = tid >> 2;
    const int apart = (tid & 3) * 8;
    const float* Ap0 = abuf + ((size_t)e * S_LEN + m0 + arow) * FF + apart;
    const float* Ap1 = abuf + ((size_t)e * S_LEN + m0 + 64 + arow) * FF + apart;
    const float* Bp0 = W2 + (size_t)e * HID * FF + (size_t)(n0 + arow) * FF + apart;
    const float* Bp1 = W2 + (size_t)e * HID * FF + (size_t)(n0 + 64 + arow) * FF + apart;

    f32x4 acc[4][4];
    #pragma unroll
    for (int m = 0; m < 4; ++m)
        #pragma unroll
        for (int n = 0; n < 4; ++n) { acc[m][n][0]=0.f; acc[m][n][1]=0.f; acc[m][n][2]=0.f; acc[m][n][3]=0.f; }

    for (int k0 = 0; k0 < FF; k0 += 32) {
        float4 a0 = ((const float4*)(Ap0 + k0))[0], a1 = ((const float4*)(Ap0 + k0))[1];
        float4 a2 = ((const float4*)(Ap1 + k0))[0], a3 = ((const float4*)(Ap1 + k0))[1];
        float4 b0 = ((const float4*)(Bp0 + k0))[0], b1 = ((const float4*)(Bp0 + k0))[1];
        float4 b2 = ((const float4*)(Bp1 + k0))[0], b3 = ((const float4*)(Bp1 + k0))[1];
        bf16x8 h8, l8;
        __syncthreads();
        split_pair(a0, a1, h8, l8);
        *(bf16x8*)&Ah[arow*40 + apart] = h8;       *(bf16x8*)&Al[arow*40 + apart] = l8;
        split_pair(a2, a3, h8, l8);
        *(bf16x8*)&Ah[(64+arow)*40 + apart] = h8;  *(bf16x8*)&Al[(64+arow)*40 + apart] = l8;
        split_pair(b0, b1, h8, l8);
        *(bf16x8*)&Bh[arow*40 + apart] = h8;       *(bf16x8*)&Bl[arow*40 + apart] = l8;
        split_pair(b2, b3, h8, l8);
        *(bf16x8*)&Bh[(64+arow)*40 + apart] = h8;  *(bf16x8*)&Bl[(64+arow)*40 + apart] = l8;
        __syncthreads();
        bf16x8 ah[4], al[4], bh[4], bl[4];
        #pragma unroll
        for (int m = 0; m < 4; ++m) {
            ah[m] = *(const bf16x8*)&Ah[(wr*64 + m*16 + lo)*40 + hi*8];
            al[m] = *(const bf16x8*)&Al[(wr*64 + m*16 + lo)*40 + hi*8];
        }
        #pragma unroll
        for (int n = 0; n < 4; ++n) {
            bh[n] = *(const bf16x8*)&Bh[(wc*64 + n*16 + lo)*40 + hi*8];
            bl[n] = *(const bf16x8*)&Bl[(wc*64 + n*16 + lo)*40 + hi*8];
        }
        #pragma unroll
        for (int m = 0; m < 4; ++m)
            #pragma unroll
            for (int n = 0; n < 4; ++n) {
                acc[m][n] = __builtin_amdgcn_mfma_f32_16x16x32_bf16(ah[m], bh[n], acc[m][n], 0, 0, 0);
                acc[m][n] = __builtin_amdgcn_mfma_f32_16x16x32_bf16(al[m], bh[n], acc[m][n], 0, 0, 0);
                acc[m][n] = __builtin_amdgcn_mfma_f32_16x16x32_bf16(ah[m], bl[n], acc[m][n], 0, 0, 0);
            }
    }
    #pragma unroll
    for (int m = 0; m < 4; ++m) {
        #pragma unroll
        for (int r = 0; r < 4; ++r) {
            int slot = m0 + wr*64 + m*16 + hi*4 + r;
            if (slot >= ne) continue;
            int tok = idx[e * S_LEN + slot];
            float wv = wt[e * S_LEN + slot];
            #pragma unroll
            for (int n = 0; n < 4; ++n)
                atomicAdd(&hbuf[(size_t)tok * HID + n0 + wc*64 + n*16 + lo], acc[m][n][r] * wv);
        }
    }
}

extern "C" void kernel_launch(void* const* d_in, const int* in_sizes, int n_in,
                              void* d_out, int out_size, void* d_ws, size_t ws_size,
                              hipStream_t stream) {
    const float* emb = (const float*)d_in[0];
    const float* ln1 = (const float*)d_in[1];
    const float* ln2 = (const float*)d_in[2];
    const float* fln = (const float*)d_in[3];
    const float* qw  = (const float*)d_in[4];
    const float* kw  = (const float*)d_in[5];
    const float* vw  = (const float*)d_in[6];
    const float* ow  = (const float*)d_in[7];
    const float* gw  = (const float*)d_in[8];
    const float* w1  = (const float*)d_in[9];
    const float* w2  = (const float*)d_in[10];
    const float* w3  = (const float*)d_in[11];

    float* ws   = (float*)d_ws;
    float* h    = ws + OFF_H;
    float* xn   = ws + OFF_XN;
    float* q    = ws + OFF_Q;
    float* kb   = ws + OFF_K;
    float* vb   = ws + OFF_V;
    float* ao   = ws + OFF_AO;
    float* cosb = ws + OFF_COS;
    float* sinb = ws + OFF_SIN;
    float* wt   = ws + OFF_WT;
    float* abuf = ws + OFF_ABUF;
    int*   cnt  = (int*)(ws + OFF_INT);
    int*   idx  = cnt + 8;

    hipMemcpyAsync(h, emb, (size_t)S_LEN * HID * sizeof(float), hipMemcpyDeviceToDevice, stream);
    rope_tables_kernel<<<S_LEN * 32 / 256, 256, 0, stream>>>(cosb, sinb);

    for (int l = 0; l < NL; ++l) {
        rmsnorm_kernel<<<S_LEN, 256, 0, stream>>>(h, ln1 + l * HID, xn);
        gemm3_mfma_kernel<<<dim3(8, 16), 256, 0, stream>>>(xn, qw + (size_t)l * HID * HID, q, nullptr, HID, HID);
        gemm3_mfma_kernel<<<dim3(2, 16), 256, 0, stream>>>(xn, kw + (size_t)l * KVH * HD * HID, kb, nullptr, KVH * HD, HID);
        gemm3_mfma_kernel<<<dim3(2, 16), 256, 0, stream>>>(xn, vw + (size_t)l * KVH * HD * HID, vb, nullptr, KVH * HD, HID);
        rope_apply_kernel<<<(S_LEN * NHEAD * 32) / 256, 256, 0, stream>>>(q, cosb, sinb, NHEAD, S_LEN * NHEAD * 32);
        rope_apply_kernel<<<(S_LEN * KVH * 32) / 256, 256, 0, stream>>>(kb, cosb, sinb, KVH, S_LEN * KVH * 32);
        attn_mfma_kernel<<<NHEAD * 32, 256, 0, stream>>>(q, kb, vb, ao);
        gemm3_mfma_kernel<<<dim3(8, 16), 256, 0, stream>>>(ao, ow + (size_t)l * HID * HID, h, h, HID, HID);
        rmsnorm_kernel<<<S_LEN, 256, 0, stream>>>(h, ln2 + l * HID, xn);
        hipMemsetAsync(cnt, 0, 8 * sizeof(int), stream);
        gate_topk_kernel<<<S_LEN, 64, 0, stream>>>(xn, gw + (size_t)l * NE * HID, cnt, idx, wt);
        moe_mlp1_mfma<<<dim3(16, 16, 8), 256, 0, stream>>>(xn, w1 + (size_t)l * NE * FF * HID,
                                                           w3 + (size_t)l * NE * FF * HID, cnt, idx, abuf);
        moe_mlp2_mfma<<<dim3(8, 16, 8), 256, 0, stream>>>(abuf, w2 + (size_t)l * NE * HID * FF, cnt, idx, wt, h);
    }
    rmsnorm_kernel<<<S_LEN, 256, 0, stream>>>(h, fln, (float*)d_out);
}

// Round 5
// 952.299 us; speedup vs baseline: 4.8049x; 1.1463x over previous
//
#include <hip/hip_runtime.h>
#include <hip/hip_bf16.h>
#include <math.h>

#define S_LEN 2048
#define HID   1024
#define NHEAD 16
#define KVH   4
#define HD    64
#define FF    1024
#define NE    8
#define NL    2

// ---- workspace layout (float offsets) ----
#define OFF_H    0
#define OFF_XN   (OFF_H + S_LEN*HID)
#define OFF_Q    (OFF_XN + S_LEN*HID)
#define OFF_K    (OFF_Q + S_LEN*HID)
#define OFF_V    (OFF_K + S_LEN*KVH*HD)
#define OFF_COS  (OFF_V + S_LEN*KVH*HD)
#define OFF_SIN  (OFF_COS + S_LEN*32)
#define OFF_WT   (OFF_SIN + S_LEN*32)
#define OFF_INT  (OFF_WT + NE*S_LEN)
#define OFF_XNH  (OFF_INT + NE*S_LEN + 16)
#define OFF_XNL  (OFF_XNH + S_LEN*HID/2)
#define OFF_AOH  (OFF_XNL + S_LEN*HID/2)
#define OFF_AOL  (OFF_AOH + S_LEN*HID/2)
#define OFF_ABH  (OFF_AOL + S_LEN*HID/2)
#define OFF_ABL  (OFF_ABH + NE*S_LEN*FF/2)
#define OFF_WSPL (OFF_ABL + NE*S_LEN*FF/2)
// WSPL region: 32M shorts (16M floats). Total ws ~= 174 MB.

typedef __attribute__((ext_vector_type(8))) short bf16x8;
typedef __attribute__((ext_vector_type(4))) float f32x4;

__device__ __forceinline__ short f2b(float f) {
    union { __hip_bfloat16 b; short s; } u;
    u.b = __float2bfloat16(f);
    return u.s;
}

__device__ __forceinline__ void split1(float x, short& h, short& l) {
    union { float f; unsigned u; } a; a.f = x;
    h = (short)(a.u >> 16);
    union { float f; unsigned u; } r; r.u = a.u & 0xFFFF0000u;
    l = f2b(x - r.f);
}

// ---------------- fp32 -> (hi,lo) bf16 split, elementwise ----------------
__global__ __launch_bounds__(256) void split_kernel(const float* __restrict__ src,
                                                    short* __restrict__ hi,
                                                    short* __restrict__ lo, int n8) {
    int gid = blockIdx.x * 256 + threadIdx.x;
    if (gid >= n8) return;
    const float4* s = (const float4*)src + (size_t)gid * 2;
    float4 a = s[0], b = s[1];
    float v[8] = {a.x, a.y, a.z, a.w, b.x, b.y, b.z, b.w};
    bf16x8 h8, l8;
    #pragma unroll
    for (int i = 0; i < 8; ++i) { short hh, ll; split1(v[i], hh, ll); h8[i]=hh; l8[i]=ll; }
    *(bf16x8*)(hi + (size_t)gid * 8) = h8;
    *(bf16x8*)(lo + (size_t)gid * 8) = l8;
}

// ---------------- RoPE tables ----------------
__global__ void rope_tables_kernel(float* __restrict__ cosb, float* __restrict__ sinb) {
    int gid = blockIdx.x * 256 + threadIdx.x;
    int t = gid >> 5, i = gid & 31;
    float invf = powf(1.0e6f, -(float)i / 32.0f);
    float ang = (float)t * invf;
    cosb[gid] = cosf(ang);
    sinb[gid] = sinf(ang);
}

// ---------------- RMSNorm -> fp32 + hi/lo bf16 ----------------
__global__ __launch_bounds__(256) void rmsnorm_split_kernel(const float* __restrict__ x,
                                                            const float* __restrict__ w,
                                                            float* __restrict__ out,
                                                            short* __restrict__ oh,
                                                            short* __restrict__ ol) {
    int row = blockIdx.x;
    const float4* xr = (const float4*)(x + (size_t)row * HID);
    float4 xv = xr[threadIdx.x];
    float ss = xv.x*xv.x + xv.y*xv.y + xv.z*xv.z + xv.w*xv.w;
    for (int off = 32; off; off >>= 1) ss += __shfl_xor(ss, off);
    __shared__ float sred[4];
    if ((threadIdx.x & 63) == 0) sred[threadIdx.x >> 6] = ss;
    __syncthreads();
    float tot = sred[0] + sred[1] + sred[2] + sred[3];
    float scale = rsqrtf(tot * (1.0f / (float)HID) + 1e-5f);
    float4 wv = ((const float4*)w)[threadIdx.x];
    float4 o;
    o.x = xv.x * scale * wv.x; o.y = xv.y * scale * wv.y;
    o.z = xv.z * scale * wv.z; o.w = xv.w * scale * wv.w;
    ((float4*)(out + (size_t)row * HID))[threadIdx.x] = o;
    union { short s[4]; float2 f2; } hh, ll;
    split1(o.x, hh.s[0], ll.s[0]); split1(o.y, hh.s[1], ll.s[1]);
    split1(o.z, hh.s[2], ll.s[2]); split1(o.w, hh.s[3], ll.s[3]);
    ((float2*)(oh + (size_t)row * HID))[threadIdx.x] = hh.f2;
    ((float2*)(ol + (size_t)row * HID))[threadIdx.x] = ll.f2;
}

// plain rmsnorm for the final output
__global__ __launch_bounds__(256) void rmsnorm_kernel(const float* __restrict__ x,
                                                      const float* __restrict__ w,
                                                      float* __restrict__ out) {
    int row = blockIdx.x;
    const float4* xr = (const float4*)(x + (size_t)row * HID);
    float4 xv = xr[threadIdx.x];
    float ss = xv.x*xv.x + xv.y*xv.y + xv.z*xv.z + xv.w*xv.w;
    for (int off = 32; off; off >>= 1) ss += __shfl_xor(ss, off);
    __shared__ float sred[4];
    if ((threadIdx.x & 63) == 0) sred[threadIdx.x >> 6] = ss;
    __syncthreads();
    float tot = sred[0] + sred[1] + sred[2] + sred[3];
    float scale = rsqrtf(tot * (1.0f / (float)HID) + 1e-5f);
    float4 wv = ((const float4*)w)[threadIdx.x];
    float4 o;
    o.x = xv.x * scale * wv.x; o.y = xv.y * scale * wv.y;
    o.z = xv.z * scale * wv.z; o.w = xv.w * scale * wv.w;
    ((float4*)(out + (size_t)row * HID))[threadIdx.x] = o;
}

// ---------------- RoPE apply ----------------
__global__ void rope_apply_kernel(float* __restrict__ p, const float* __restrict__ cosb,
                                  const float* __restrict__ sinb, int nh, int total) {
    int gid = blockIdx.x * 256 + threadIdx.x;
    if (gid >= total) return;
    int per = nh * 32;
    int t = gid / per, r = gid % per;
    int hh = r >> 5, i = r & 31;
    float c = cosb[t*32 + i], s = sinb[t*32 + i];
    float* base = p + (size_t)t * (nh * HD) + hh * HD + i;
    float a = base[0], b = base[32];
    base[0]  = a * c - b * s;
    base[32] = b * c + a * s;
}

// ---------------- shared 128x128 3-pass GEMM core (pre-split operands) ----------------
__device__ __forceinline__ void gemm128_core(
        const short* pA0h, const short* pA1h, const short* pA0l, const short* pA1l,
        const short* pB0h, const short* pB1h, const short* pB0l, const short* pB1l,
        int Kd, int tid, short* Ah, short* Al, short* Bh, short* Bl, f32x4 (&acc)[4][4]) {
    const int lane = tid & 63, lo = lane & 15, hi = lane >> 4;
    const int wid = tid >> 6, wr = wid >> 1, wc = wid & 1;
    const int srow = tid >> 2, scol = (tid & 3) * 8;
    for (int k0 = 0; k0 < Kd; k0 += 32) {
        bf16x8 a0 = *(const bf16x8*)(pA0h + k0);
        bf16x8 a1 = *(const bf16x8*)(pA1h + k0);
        bf16x8 a2 = *(const bf16x8*)(pA0l + k0);
        bf16x8 a3 = *(const bf16x8*)(pA1l + k0);
        bf16x8 b0 = *(const bf16x8*)(pB0h + k0);
        bf16x8 b1 = *(const bf16x8*)(pB1h + k0);
        bf16x8 b2 = *(const bf16x8*)(pB0l + k0);
        bf16x8 b3 = *(const bf16x8*)(pB1l + k0);
        __syncthreads();
        *(bf16x8*)&Ah[srow*40 + scol] = a0;
        *(bf16x8*)&Ah[(64+srow)*40 + scol] = a1;
        *(bf16x8*)&Al[srow*40 + scol] = a2;
        *(bf16x8*)&Al[(64+srow)*40 + scol] = a3;
        *(bf16x8*)&Bh[srow*40 + scol] = b0;
        *(bf16x8*)&Bh[(64+srow)*40 + scol] = b1;
        *(bf16x8*)&Bl[srow*40 + scol] = b2;
        *(bf16x8*)&Bl[(64+srow)*40 + scol] = b3;
        __syncthreads();
        bf16x8 ah[4], al[4], bh[4], bl[4];
        #pragma unroll
        for (int m = 0; m < 4; ++m) {
            ah[m] = *(const bf16x8*)&Ah[(wr*64 + m*16 + lo)*40 + hi*8];
            al[m] = *(const bf16x8*)&Al[(wr*64 + m*16 + lo)*40 + hi*8];
        }
        #pragma unroll
        for (int n = 0; n < 4; ++n) {
            bh[n] = *(const bf16x8*)&Bh[(wc*64 + n*16 + lo)*40 + hi*8];
            bl[n] = *(const bf16x8*)&Bl[(wc*64 + n*16 + lo)*40 + hi*8];
        }
        #pragma unroll
        for (int m = 0; m < 4; ++m)
            #pragma unroll
            for (int n = 0; n < 4; ++n) {
                acc[m][n] = __builtin_amdgcn_mfma_f32_16x16x32_bf16(ah[m], bh[n], acc[m][n], 0, 0, 0);
                acc[m][n] = __builtin_amdgcn_mfma_f32_16x16x32_bf16(al[m], bh[n], acc[m][n], 0, 0, 0);
                acc[m][n] = __builtin_amdgcn_mfma_f32_16x16x32_bf16(ah[m], bl[n], acc[m][n], 0, 0, 0);
            }
    }
}

// ---------------- generic pre-split GEMM: C = A@B^T (+resid) ----------------
__global__ __launch_bounds__(256) void gemm3ps_kernel(const short* __restrict__ Ahg,
        const short* __restrict__ Alg, const short* __restrict__ Bhg, const short* __restrict__ Blg,
        float* __restrict__ C, const float* __restrict__ resid, int N, int Kd) {
    __shared__ __align__(16) short Ah[128*40], Al[128*40], Bh[128*40], Bl[128*40];
    const int tid = threadIdx.x;
    const int lane = tid & 63, lo = lane & 15, hi = lane >> 4;
    const int wid = tid >> 6, wr = wid >> 1, wc = wid & 1;
    const int m0 = blockIdx.y * 128, n0 = blockIdx.x * 128;
    const int srow = tid >> 2, scol = (tid & 3) * 8;
    f32x4 acc[4][4];
    #pragma unroll
    for (int m = 0; m < 4; ++m)
        #pragma unroll
        for (int n = 0; n < 4; ++n) { acc[m][n][0]=0.f; acc[m][n][1]=0.f; acc[m][n][2]=0.f; acc[m][n][3]=0.f; }
    gemm128_core(Ahg + (size_t)(m0+srow)*Kd + scol,   Ahg + (size_t)(m0+64+srow)*Kd + scol,
                 Alg + (size_t)(m0+srow)*Kd + scol,   Alg + (size_t)(m0+64+srow)*Kd + scol,
                 Bhg + (size_t)(n0+srow)*Kd + scol,   Bhg + (size_t)(n0+64+srow)*Kd + scol,
                 Blg + (size_t)(n0+srow)*Kd + scol,   Blg + (size_t)(n0+64+srow)*Kd + scol,
                 Kd, tid, Ah, Al, Bh, Bl, acc);
    #pragma unroll
    for (int m = 0; m < 4; ++m)
        #pragma unroll
        for (int n = 0; n < 4; ++n)
            #pragma unroll
            for (int r = 0; r < 4; ++r) {
                int row = m0 + wr*64 + m*16 + hi*4 + r;
                int col = n0 + wc*64 + n*16 + lo;
                float val = acc[m][n][r];
                if (resid) val += resid[(size_t)row * N + col];
                C[(size_t)row * N + col] = val;
            }
}

// ---------------- fused QKV GEMM (pre-split) ----------------
__global__ __launch_bounds__(256) void qkv_mfma_kernel(const short* __restrict__ Xh,
        const short* __restrict__ Xl,
        const short* __restrict__ qh, const short* __restrict__ ql,
        const short* __restrict__ kh, const short* __restrict__ kl,
        const short* __restrict__ vh, const short* __restrict__ vl,
        float* __restrict__ qo, float* __restrict__ ko, float* __restrict__ vo) {
    __shared__ __align__(16) short Ah[128*40], Al[128*40], Bh[128*40], Bl[128*40];
    const int bx = blockIdx.x;
    const short *Bhp, *Blp; float* Cp; int Nc, n0;
    if (bx < 8)       { Bhp = qh; Blp = ql; Cp = qo; Nc = 1024; n0 = bx * 128; }
    else if (bx < 10) { Bhp = kh; Blp = kl; Cp = ko; Nc = 256;  n0 = (bx - 8) * 128; }
    else              { Bhp = vh; Blp = vl; Cp = vo; Nc = 256;  n0 = (bx - 10) * 128; }
    const int tid = threadIdx.x;
    const int lane = tid & 63, lo = lane & 15, hi = lane >> 4;
    const int wid = tid >> 6, wr = wid >> 1, wc = wid & 1;
    const int m0 = blockIdx.y * 128;
    const int srow = tid >> 2, scol = (tid & 3) * 8;
    f32x4 acc[4][4];
    #pragma unroll
    for (int m = 0; m < 4; ++m)
        #pragma unroll
        for (int n = 0; n < 4; ++n) { acc[m][n][0]=0.f; acc[m][n][1]=0.f; acc[m][n][2]=0.f; acc[m][n][3]=0.f; }
    gemm128_core(Xh + (size_t)(m0+srow)*HID + scol,   Xh + (size_t)(m0+64+srow)*HID + scol,
                 Xl + (size_t)(m0+srow)*HID + scol,   Xl + (size_t)(m0+64+srow)*HID + scol,
                 Bhp + (size_t)(n0+srow)*HID + scol,  Bhp + (size_t)(n0+64+srow)*HID + scol,
                 Blp + (size_t)(n0+srow)*HID + scol,  Blp + (size_t)(n0+64+srow)*HID + scol,
                 HID, tid, Ah, Al, Bh, Bl, acc);
    #pragma unroll
    for (int m = 0; m < 4; ++m)
        #pragma unroll
        for (int n = 0; n < 4; ++n)
            #pragma unroll
            for (int r = 0; r < 4; ++r) {
                int row = m0 + wr*64 + m*16 + hi*4 + r;
                int col = n0 + wc*64 + n*16 + lo;
                Cp[(size_t)row * Nc + col] = acc[m][n][r];
            }
}

// ---------------- MFMA flash attention; epilogue writes hi/lo ----------------
__global__ __launch_bounds__(256) void attn_mfma_kernel(const float* __restrict__ q,
                                                        const float* __restrict__ k,
                                                        const float* __restrict__ v,
                                                        short* __restrict__ aoh,
                                                        short* __restrict__ aol) {
    __shared__ __align__(16) short Ks[64][72];
    __shared__ __align__(16) short Vt[64][72];
    __shared__ __align__(16) short Ps[4][16][72];
    const int wid = threadIdx.x >> 6, lane = threadIdx.x & 63;
    const int lo = lane & 15, hi = lane >> 4;
    const int head = blockIdx.x >> 5;
    const int qi = blockIdx.x & 31;
    const int q0 = (31 - qi) * 64;
    const int kvh = head >> 2;

    bf16x8 qf[2];
    {
        const float* qr = q + (size_t)(q0 + wid*16 + lo) * HID + head*HD;
        #pragma unroll
        for (int kk = 0; kk < 2; ++kk)
            #pragma unroll
            for (int i = 0; i < 8; ++i)
                qf[kk][i] = f2b(qr[kk*32 + hi*8 + i]);
    }

    f32x4 acc[4];
    float m[4], l[4];
    #pragma unroll
    for (int r = 0; r < 4; ++r) {
        m[r] = -1e30f; l[r] = 0.f;
        acc[0][r] = 0.f; acc[1][r] = 0.f; acc[2][r] = 0.f; acc[3][r] = 0.f;
    }

    const int ntiles = q0/64 + 1;
    const int skey = threadIdx.x >> 2;
    const int sdg  = (threadIdx.x & 3) * 16;

    for (int t = 0; t < ntiles; ++t) {
        const int k0 = t * 64;
        __syncthreads();
        {
            const float* kr = k + (size_t)(k0 + skey)*(KVH*HD) + kvh*HD + sdg;
            float4 a0 = ((const float4*)kr)[0], a1 = ((const float4*)kr)[1],
                   a2 = ((const float4*)kr)[2], a3 = ((const float4*)kr)[3];
            bf16x8 w0, w1;
            w0[0]=f2b(a0.x); w0[1]=f2b(a0.y); w0[2]=f2b(a0.z); w0[3]=f2b(a0.w);
            w0[4]=f2b(a1.x); w0[5]=f2b(a1.y); w0[6]=f2b(a1.z); w0[7]=f2b(a1.w);
            w1[0]=f2b(a2.x); w1[1]=f2b(a2.y); w1[2]=f2b(a2.z); w1[3]=f2b(a2.w);
            w1[4]=f2b(a3.x); w1[5]=f2b(a3.y); w1[6]=f2b(a3.z); w1[7]=f2b(a3.w);
            *(bf16x8*)&Ks[skey][sdg]     = w0;
            *(bf16x8*)&Ks[skey][sdg + 8] = w1;
            const float* vr = v + (size_t)(k0 + skey)*(KVH*HD) + kvh*HD + sdg;
            float4 b0 = ((const float4*)vr)[0], b1 = ((const float4*)vr)[1],
                   b2 = ((const float4*)vr)[2], b3 = ((const float4*)vr)[3];
            Vt[sdg+ 0][skey]=f2b(b0.x); Vt[sdg+ 1][skey]=f2b(b0.y);
            Vt[sdg+ 2][skey]=f2b(b0.z); Vt[sdg+ 3][skey]=f2b(b0.w);
            Vt[sdg+ 4][skey]=f2b(b1.x); Vt[sdg+ 5][skey]=f2b(b1.y);
            Vt[sdg+ 6][skey]=f2b(b1.z); Vt[sdg+ 7][skey]=f2b(b1.w);
            Vt[sdg+ 8][skey]=f2b(b2.x); Vt[sdg+ 9][skey]=f2b(b2.y);
            Vt[sdg+10][skey]=f2b(b2.z); Vt[sdg+11][skey]=f2b(b2.w);
            Vt[sdg+12][skey]=f2b(b3.x); Vt[sdg+13][skey]=f2b(b3.y);
            Vt[sdg+14][skey]=f2b(b3.z); Vt[sdg+15][skey]=f2b(b3.w);
        }
        __syncthreads();
        f32x4 s[4];
        #pragma unroll
        for (int f = 0; f < 4; ++f) {
            f32x4 sf; sf[0]=0.f; sf[1]=0.f; sf[2]=0.f; sf[3]=0.f;
            bf16x8 bk0 = *(const bf16x8*)&Ks[f*16 + lo][hi*8];
            sf = __builtin_amdgcn_mfma_f32_16x16x32_bf16(qf[0], bk0, sf, 0, 0, 0);
            bf16x8 bk1 = *(const bf16x8*)&Ks[f*16 + lo][32 + hi*8];
            sf = __builtin_amdgcn_mfma_f32_16x16x32_bf16(qf[1], bk1, sf, 0, 0, 0);
            s[f] = sf;
        }
        #pragma unroll
        for (int f = 0; f < 4; ++f)
            #pragma unroll
            for (int r = 0; r < 4; ++r) s[f][r] *= 0.125f;
        if (t == ntiles - 1) {
            int qrow = q0 + wid*16 + hi*4;
            #pragma unroll
            for (int f = 0; f < 4; ++f)
                #pragma unroll
                for (int r = 0; r < 4; ++r)
                    if (k0 + f*16 + lo > qrow + r) s[f][r] = -1e30f;
        }
        float sc_[4];
        #pragma unroll
        for (int r = 0; r < 4; ++r) {
            float x = fmaxf(fmaxf(s[0][r], s[1][r]), fmaxf(s[2][r], s[3][r]));
            x = fmaxf(x, __shfl_xor(x, 1));
            x = fmaxf(x, __shfl_xor(x, 2));
            x = fmaxf(x, __shfl_xor(x, 4));
            x = fmaxf(x, __shfl_xor(x, 8));
            float mn = fmaxf(m[r], x);
            sc_[r] = __expf(m[r] - mn);
            m[r] = mn;
            l[r] *= sc_[r];
            acc[0][r] *= sc_[r]; acc[1][r] *= sc_[r];
            acc[2][r] *= sc_[r]; acc[3][r] *= sc_[r];
        }
        float rs[4] = {0.f, 0.f, 0.f, 0.f};
        #pragma unroll
        for (int f = 0; f < 4; ++f)
            #pragma unroll
            for (int r = 0; r < 4; ++r) {
                float e = __expf(s[f][r] - m[r]);
                rs[r] += e;
                Ps[wid][hi*4 + r][f*16 + lo] = f2b(e);
            }
        #pragma unroll
        for (int r = 0; r < 4; ++r) {
            float x = rs[r];
            x += __shfl_xor(x, 1); x += __shfl_xor(x, 2);
            x += __shfl_xor(x, 4); x += __shfl_xor(x, 8);
            l[r] += x;
        }
        asm volatile("s_waitcnt lgkmcnt(0)" ::: "memory");
        __builtin_amdgcn_sched_barrier(0);
        bf16x8 pa0 = *(const bf16x8*)&Ps[wid][lo][hi*8];
        bf16x8 pa1 = *(const bf16x8*)&Ps[wid][lo][32 + hi*8];
        #pragma unroll
        for (int f = 0; f < 4; ++f) {
            f32x4 o = acc[f];
            bf16x8 v0 = *(const bf16x8*)&Vt[f*16 + lo][hi*8];
            o = __builtin_amdgcn_mfma_f32_16x16x32_bf16(pa0, v0, o, 0, 0, 0);
            bf16x8 v1 = *(const bf16x8*)&Vt[f*16 + lo][32 + hi*8];
            o = __builtin_amdgcn_mfma_f32_16x16x32_bf16(pa1, v1, o, 0, 0, 0);
            acc[f] = o;
        }
    }
    #pragma unroll
    for (int r = 0; r < 4; ++r) {
        float inv = 1.0f / l[r];
        #pragma unroll
        for (int f = 0; f < 4; ++f) {
            float val = acc[f][r] * inv;
            size_t o = (size_t)(q0 + wid*16 + hi*4 + r) * HID + head*HD + f*16 + lo;
            short hh, ll; split1(val, hh, ll);
            aoh[o] = hh; aol[o] = ll;
        }
    }
}

// ---------------- gate + top-2 routing (exact fp32) ----------------
__global__ __launch_bounds__(64) void gate_topk_kernel(const float* __restrict__ xn,
                                                       const float* __restrict__ gw,
                                                       int* __restrict__ cnt,
                                                       int* __restrict__ idx,
                                                       float* __restrict__ wt) {
    int t = blockIdx.x, lane = threadIdx.x;
    float acc[NE] = {};
    for (int i = lane; i < HID; i += 64) {
        float x = xn[(size_t)t * HID + i];
        #pragma unroll
        for (int e = 0; e < NE; ++e) acc[e] += x * gw[e * HID + i];
    }
    #pragma unroll
    for (int e = 0; e < NE; ++e)
        for (int off = 32; off; off >>= 1) acc[e] += __shfl_xor(acc[e], off);
    if (lane == 0) {
        float mx = acc[0];
        #pragma unroll
        for (int e = 1; e < NE; ++e) mx = fmaxf(mx, acc[e]);
        float p[NE];
        #pragma unroll
        for (int e = 0; e < NE; ++e) p[e] = __expf(acc[e] - mx);
        int i0 = 0;
        #pragma unroll
        for (int e = 1; e < NE; ++e) if (p[e] > p[i0]) i0 = e;
        int i1 = -1;
        #pragma unroll
        for (int e = 0; e < NE; ++e) if (e != i0 && (i1 < 0 || p[e] > p[i1])) i1 = e;
        float w0 = p[i0], w1 = p[i1];
        float inv = 1.0f / (w0 + w1);
        int s0 = atomicAdd(&cnt[i0], 1);
        idx[i0 * S_LEN + s0] = t; wt[i0 * S_LEN + s0] = w0 * inv;
        int s1 = atomicAdd(&cnt[i1], 1);
        idx[i1 * S_LEN + s1] = t; wt[i1 * S_LEN + s1] = w1 * inv;
    }
}

// ---------------- MoE mlp1 (pre-split): ab = silu(x@w1^T)*(x@w3^T) -> hi/lo ----------------
__global__ __launch_bounds__(256) void moe_mlp1_ps(const short* __restrict__ Xh,
        const short* __restrict__ Xl,
        const short* __restrict__ W1h, const short* __restrict__ W1l,
        const short* __restrict__ W3h, const short* __restrict__ W3l,
        const int* __restrict__ cnt, const int* __restrict__ idx,
        short* __restrict__ abh, short* __restrict__ abl) {
    int e = blockIdx.z;
    int ne = cnt[e];
    int m0 = blockIdx.y * 128;
    if (m0 >= ne) return;
    int f0 = blockIdx.x * 64;
    __shared__ __align__(16) short Ah[128*40], Al[128*40];
    __shared__ __align__(16) short Gh[64*40], Gl[64*40], Uh[64*40], Ul[64*40];
    __shared__ int rows[128];
    const int tid = threadIdx.x;
    if (tid < 128) {
        int slot = m0 + tid;
        rows[tid] = (slot < ne) ? idx[e * S_LEN + slot] : 0;
    }
    __syncthreads();
    const int lane = tid & 63, lo = lane & 15, hi = lane >> 4;
    const int wid = tid >> 6, wr = wid >> 1, wc = wid & 1;
    const int srow = tid >> 2, scol = (tid & 3) * 8;
    const short* pXh0 = Xh + (size_t)rows[srow] * HID + scol;
    const short* pXh1 = Xh + (size_t)rows[64 + srow] * HID + scol;
    const short* pXl0 = Xl + (size_t)rows[srow] * HID + scol;
    const short* pXl1 = Xl + (size_t)rows[64 + srow] * HID + scol;
    const short* p1h = W1h + ((size_t)e * FF + f0 + srow) * HID + scol;
    const short* p1l = W1l + ((size_t)e * FF + f0 + srow) * HID + scol;
    const short* p3h = W3h + ((size_t)e * FF + f0 + srow) * HID + scol;
    const short* p3l = W3l + ((size_t)e * FF + f0 + srow) * HID + scol;

    f32x4 ag[4][2], au[4][2];
    #pragma unroll
    for (int m = 0; m < 4; ++m)
        #pragma unroll
        for (int n = 0; n < 2; ++n) {
            ag[m][n][0]=0.f; ag[m][n][1]=0.f; ag[m][n][2]=0.f; ag[m][n][3]=0.f;
            au[m][n][0]=0.f; au[m][n][1]=0.f; au[m][n][2]=0.f; au[m][n][3]=0.f;
        }

    for (int k0 = 0; k0 < HID; k0 += 32) {
        bf16x8 a0 = *(const bf16x8*)(pXh0 + k0);
        bf16x8 a1 = *(const bf16x8*)(pXh1 + k0);
        bf16x8 a2 = *(const bf16x8*)(pXl0 + k0);
        bf16x8 a3 = *(const bf16x8*)(pXl1 + k0);
        bf16x8 g0 = *(const bf16x8*)(p1h + k0);
        bf16x8 g1 = *(const bf16x8*)(p1l + k0);
        bf16x8 u0 = *(const bf16x8*)(p3h + k0);
        bf16x8 u1 = *(const bf16x8*)(p3l + k0);
        __syncthreads();
        *(bf16x8*)&Ah[srow*40 + scol] = a0;
        *(bf16x8*)&Ah[(64+srow)*40 + scol] = a1;
        *(bf16x8*)&Al[srow*40 + scol] = a2;
        *(bf16x8*)&Al[(64+srow)*40 + scol] = a3;
        *(bf16x8*)&Gh[srow*40 + scol] = g0;
        *(bf16x8*)&Gl[srow*40 + scol] = g1;
        *(bf16x8*)&Uh[srow*40 + scol] = u0;
        *(bf16x8*)&Ul[srow*40 + scol] = u1;
        __syncthreads();
        bf16x8 ah[4], al[4], gh[2], gl[2], uh[2], ul[2];
        #pragma unroll
        for (int m = 0; m < 4; ++m) {
            ah[m] = *(const bf16x8*)&Ah[(wr*64 + m*16 + lo)*40 + hi*8];
            al[m] = *(const bf16x8*)&Al[(wr*64 + m*16 + lo)*40 + hi*8];
        }
        #pragma unroll
        for (int n = 0; n < 2; ++n) {
            gh[n] = *(const bf16x8*)&Gh[(wc*32 + n*16 + lo)*40 + hi*8];
            gl[n] = *(const bf16x8*)&Gl[(wc*32 + n*16 + lo)*40 + hi*8];
            uh[n] = *(const bf16x8*)&Uh[(wc*32 + n*16 + lo)*40 + hi*8];
            ul[n] = *(const bf16x8*)&Ul[(wc*32 + n*16 + lo)*40 + hi*8];
        }
        #pragma unroll
        for (int m = 0; m < 4; ++m)
            #pragma unroll
            for (int n = 0; n < 2; ++n) {
                ag[m][n] = __builtin_amdgcn_mfma_f32_16x16x32_bf16(ah[m], gh[n], ag[m][n], 0, 0, 0);
                ag[m][n] = __builtin_amdgcn_mfma_f32_16x16x32_bf16(al[m], gh[n], ag[m][n], 0, 0, 0);
                ag[m][n] = __builtin_amdgcn_mfma_f32_16x16x32_bf16(ah[m], gl[n], ag[m][n], 0, 0, 0);
                au[m][n] = __builtin_amdgcn_mfma_f32_16x16x32_bf16(ah[m], uh[n], au[m][n], 0, 0, 0);
                au[m][n] = __builtin_amdgcn_mfma_f32_16x16x32_bf16(al[m], uh[n], au[m][n], 0, 0, 0);
                au[m][n] = __builtin_amdgcn_mfma_f32_16x16x32_bf16(ah[m], ul[n], au[m][n], 0, 0, 0);
            }
    }
    #pragma unroll
    for (int m = 0; m < 4; ++m)
        #pragma unroll
        for (int n = 0; n < 2; ++n)
            #pragma unroll
            for (int r = 0; r < 4; ++r) {
                int slot = m0 + wr*64 + m*16 + hi*4 + r;
                if (slot >= ne) continue;
                float g = ag[m][n][r], u = au[m][n][r];
                float a = g * (1.0f / (1.0f + __expf(-g))) * u;
                size_t o = ((size_t)e * S_LEN + slot) * FF + f0 + wc*32 + n*16 + lo;
                short hh, ll; split1(a, hh, ll);
                abh[o] = hh; abl[o] = ll;
            }
}

// ---------------- MoE mlp2 (pre-split): h += wt * (a @ w2^T) ----------------
__global__ __launch_bounds__(256) void moe_mlp2_ps(const short* __restrict__ abh,
        const short* __restrict__ abl,
        const short* __restrict__ W2h, const short* __restrict__ W2l,
        const int* __restrict__ cnt, const int* __restrict__ idx,
        const float* __restrict__ wt, float* __restrict__ hbuf) {
    int e = blockIdx.z;
    int ne = cnt[e];
    int m0 = blockIdx.y * 128;
    if (m0 >= ne) return;
    int n0 = blockIdx.x * 128;
    __shared__ __align__(16) short Ah[128*40], Al[128*40], Bh[128*40], Bl[128*40];
    const int tid = threadIdx.x;
    const int lane = tid & 63, lo = lane & 15, hi = lane >> 4;
    const int wid = tid >> 6, wr = wid >> 1, wc = wid & 1;
    const int srow = tid >> 2, scol = (tid & 3) * 8;
    f32x4 acc[4][4];
    #pragma unroll
    for (int m = 0; m < 4; ++m)
        #pragma unroll
        for (int n = 0; n < 4; ++n) { acc[m][n][0]=0.f; acc[m][n][1]=0.f; acc[m][n][2]=0.f; acc[m][n][3]=0.f; }
    gemm128_core(abh + ((size_t)e*S_LEN + m0 + srow)*FF + scol,
                 abh + ((size_t)e*S_LEN + m0 + 64 + srow)*FF + scol,
                 abl + ((size_t)e*S_LEN + m0 + srow)*FF + scol,
                 abl + ((size_t)e*S_LEN + m0 + 64 + srow)*FF + scol,
                 W2h + ((size_t)e*HID + n0 + srow)*FF + scol,
                 W2h + ((size_t)e*HID + n0 + 64 + srow)*FF + scol,
                 W2l + ((size_t)e*HID + n0 + srow)*FF + scol,
                 W2l + ((size_t)e*HID + n0 + 64 + srow)*FF + scol,
                 FF, tid, Ah, Al, Bh, Bl, acc);
    #pragma unroll
    for (int m = 0; m < 4; ++m) {
        #pragma unroll
        for (int r = 0; r < 4; ++r) {
            int slot = m0 + wr*64 + m*16 + hi*4 + r;
            if (slot >= ne) continue;
            int tok = idx[e * S_LEN + slot];
            float wv = wt[e * S_LEN + slot];
            #pragma unroll
            for (int n = 0; n < 4; ++n)
                atomicAdd(&hbuf[(size_t)tok * HID + n0 + wc*64 + n*16 + lo], acc[m][n][r] * wv);
        }
    }
}

extern "C" void kernel_launch(void* const* d_in, const int* in_sizes, int n_in,
                              void* d_out, int out_size, void* d_ws, size_t ws_size,
                              hipStream_t stream) {
    const float* emb = (const float*)d_in[0];
    const float* ln1 = (const float*)d_in[1];
    const float* ln2 = (const float*)d_in[2];
    const float* fln = (const float*)d_in[3];
    const float* qw  = (const float*)d_in[4];
    const float* kw  = (const float*)d_in[5];
    const float* vw  = (const float*)d_in[6];
    const float* ow  = (const float*)d_in[7];
    const float* gw  = (const float*)d_in[8];
    const float* w1  = (const float*)d_in[9];
    const float* w2  = (const float*)d_in[10];
    const float* w3  = (const float*)d_in[11];

    float* ws   = (float*)d_ws;
    float* h    = ws + OFF_H;
    float* xn   = ws + OFF_XN;
    float* q    = ws + OFF_Q;
    float* kb   = ws + OFF_K;
    float* vb   = ws + OFF_V;
    float* cosb = ws + OFF_COS;
    float* sinb = ws + OFF_SIN;
    float* wt   = ws + OFF_WT;
    int*   cnt  = (int*)(ws + OFF_INT);
    int*   idx  = cnt + 8;
    short* xnh  = (short*)(ws + OFF_XNH);
    short* xnl  = (short*)(ws + OFF_XNL);
    short* aoh  = (short*)(ws + OFF_AOH);
    short* aol  = (short*)(ws + OFF_AOL);
    short* abh  = (short*)(ws + OFF_ABH);
    short* abl  = (short*)(ws + OFF_ABL);
    short* WS   = (short*)(ws + OFF_WSPL);

    // stage A layout (shorts): qkvo
    short* sqh = WS;
    short* sql = sqh + HID*HID;
    short* skh = sql + HID*HID;
    short* skl = skh + KVH*HD*HID;
    short* svh = skl + KVH*HD*HID;
    short* svl = svh + KVH*HD*HID;
    short* soh = svl + KVH*HD*HID;
    short* sol = soh + HID*HID;
    // stage B layout: w1 + w3 (full region)
    short* s1h = WS;
    short* s1l = s1h + (size_t)NE*FF*HID;
    short* s3h = s1l + (size_t)NE*FF*HID;
    short* s3l = s3h + (size_t)NE*FF*HID;
    // stage C layout: w2
    short* s2h = WS;
    short* s2l = s2h + (size_t)NE*HID*FF;

    hipMemcpyAsync(h, emb, (size_t)S_LEN * HID * sizeof(float), hipMemcpyDeviceToDevice, stream);
    rope_tables_kernel<<<S_LEN * 32 / 256, 256, 0, stream>>>(cosb, sinb);

    const int n8_qo = HID*HID/8, n8_kv = KVH*HD*HID/8, n8_w = NE*FF*HID/8;

    for (int l = 0; l < NL; ++l) {
        // stage A: split qkvo weights
        split_kernel<<<n8_qo/256, 256, 0, stream>>>(qw + (size_t)l*HID*HID, sqh, sql, n8_qo);
        split_kernel<<<n8_kv/256, 256, 0, stream>>>(kw + (size_t)l*KVH*HD*HID, skh, skl, n8_kv);
        split_kernel<<<n8_kv/256, 256, 0, stream>>>(vw + (size_t)l*KVH*HD*HID, svh, svl, n8_kv);
        split_kernel<<<n8_qo/256, 256, 0, stream>>>(ow + (size_t)l*HID*HID, soh, sol, n8_qo);

        rmsnorm_split_kernel<<<S_LEN, 256, 0, stream>>>(h, ln1 + l * HID, xn, xnh, xnl);
        qkv_mfma_kernel<<<dim3(12, 16), 256, 0, stream>>>(xnh, xnl, sqh, sql, skh, skl, svh, svl, q, kb, vb);
        rope_apply_kernel<<<(S_LEN * NHEAD * 32) / 256, 256, 0, stream>>>(q, cosb, sinb, NHEAD, S_LEN * NHEAD * 32);
        rope_apply_kernel<<<(S_LEN * KVH * 32) / 256, 256, 0, stream>>>(kb, cosb, sinb, KVH, S_LEN * KVH * 32);
        attn_mfma_kernel<<<NHEAD * 32, 256, 0, stream>>>(q, kb, vb, aoh, aol);
        gemm3ps_kernel<<<dim3(8, 16), 256, 0, stream>>>(aoh, aol, soh, sol, h, h, HID, HID);

        rmsnorm_split_kernel<<<S_LEN, 256, 0, stream>>>(h, ln2 + l * HID, xn, xnh, xnl);
        hipMemsetAsync(cnt, 0, 8 * sizeof(int), stream);
        gate_topk_kernel<<<S_LEN, 64, 0, stream>>>(xn, gw + (size_t)l * NE * HID, cnt, idx, wt);

        // stage B: split w1, w3
        split_kernel<<<n8_w/256, 256, 0, stream>>>(w1 + (size_t)l*NE*FF*HID, s1h, s1l, n8_w);
        split_kernel<<<n8_w/256, 256, 0, stream>>>(w3 + (size_t)l*NE*FF*HID, s3h, s3l, n8_w);
        moe_mlp1_ps<<<dim3(16, 16, 8), 256, 0, stream>>>(xnh, xnl, s1h, s1l, s3h, s3l, cnt, idx, abh, abl);

        // stage C: split w2 (reuses region; mlp1 completed by stream order)
        split_kernel<<<n8_w/256, 256, 0, stream>>>(w2 + (size_t)l*NE*HID*FF, s2h, s2l, n8_w);
        moe_mlp2_ps<<<dim3(8, 16, 8), 256, 0, stream>>>(abh, abl, s2h, s2l, cnt, idx, wt, h);
    }
    rmsnorm_kernel<<<S_LEN, 256, 0, stream>>>(h, fln, (float*)d_out);
}

// Round 6
// 716.925 us; speedup vs baseline: 6.3824x; 1.3283x over previous
//
#include <hip/hip_runtime.h>
#include <hip/hip_bf16.h>
#include <math.h>

#define S_LEN 2048
#define HID   1024
#define NHEAD 16
#define KVH   4
#define HD    64
#define FF    1024
#define NE    8
#define NL    2

// ---- workspace layout (float offsets) ----
#define OFF_H    0
#define OFF_XN   (OFF_H + S_LEN*HID)
#define OFF_Q    (OFF_XN + S_LEN*HID)
#define OFF_K    (OFF_Q + S_LEN*HID)
#define OFF_V    (OFF_K + S_LEN*KVH*HD)
#define OFF_COS  (OFF_V + S_LEN*KVH*HD)
#define OFF_SIN  (OFF_COS + S_LEN*32)
#define OFF_WT   (OFF_SIN + S_LEN*32)
#define OFF_INT  (OFF_WT + NE*S_LEN)
#define OFF_XH   (OFF_INT + NE*S_LEN + 16)
#define OFF_AOH  (OFF_XH + S_LEN*HID/2)
#define OFF_ABH  (OFF_AOH + S_LEN*HID/2)
#define OFF_WCVT (OFF_ABH + NE*S_LEN*FF/2)
// WCVT region (shorts): qkvo 2.5M + w1 8M + w3 8M + w2 8M = 26.5M shorts = 53MB

typedef __attribute__((ext_vector_type(8))) _Float16 f16x8;
typedef __attribute__((ext_vector_type(8))) short  s16x8;
typedef __attribute__((ext_vector_type(4))) float  f32x4;

__device__ __forceinline__ short f2h(float f) {
    union { _Float16 h; short s; } u;
    u.h = (_Float16)f;
    return u.s;
}

__device__ __forceinline__ s16x8 cvt8(float4 a, float4 b) {
    s16x8 w;
    w[0]=f2h(a.x); w[1]=f2h(a.y); w[2]=f2h(a.z); w[3]=f2h(a.w);
    w[4]=f2h(b.x); w[5]=f2h(b.y); w[6]=f2h(b.z); w[7]=f2h(b.w);
    return w;
}

// ---------------- fp32 -> fp16 convert ----------------
__global__ __launch_bounds__(256) void cvt16_kernel(const float* __restrict__ src,
                                                    short* __restrict__ dst, int n8) {
    int gid = blockIdx.x * 256 + threadIdx.x;
    if (gid >= n8) return;
    const float4* s = (const float4*)src + (size_t)gid * 2;
    *(s16x8*)(dst + (size_t)gid * 8) = cvt8(s[0], s[1]);
}

// ---------------- RoPE tables ----------------
__global__ void rope_tables_kernel(float* __restrict__ cosb, float* __restrict__ sinb) {
    int gid = blockIdx.x * 256 + threadIdx.x;
    int t = gid >> 5, i = gid & 31;
    float invf = powf(1.0e6f, -(float)i / 32.0f);
    float ang = (float)t * invf;
    cosb[gid] = cosf(ang);
    sinb[gid] = sinf(ang);
}

// ---------------- RMSNorm -> fp32 + fp16 ----------------
__global__ __launch_bounds__(256) void rmsnorm_h16_kernel(const float* __restrict__ x,
                                                          const float* __restrict__ w,
                                                          float* __restrict__ out,
                                                          short* __restrict__ oh) {
    int row = blockIdx.x;
    const float4* xr = (const float4*)(x + (size_t)row * HID);
    float4 xv = xr[threadIdx.x];
    float ss = xv.x*xv.x + xv.y*xv.y + xv.z*xv.z + xv.w*xv.w;
    for (int off = 32; off; off >>= 1) ss += __shfl_xor(ss, off);
    __shared__ float sred[4];
    if ((threadIdx.x & 63) == 0) sred[threadIdx.x >> 6] = ss;
    __syncthreads();
    float tot = sred[0] + sred[1] + sred[2] + sred[3];
    float scale = rsqrtf(tot * (1.0f / (float)HID) + 1e-5f);
    float4 wv = ((const float4*)w)[threadIdx.x];
    float4 o;
    o.x = xv.x * scale * wv.x; o.y = xv.y * scale * wv.y;
    o.z = xv.z * scale * wv.z; o.w = xv.w * scale * wv.w;
    ((float4*)(out + (size_t)row * HID))[threadIdx.x] = o;
    union { short s[4]; float2 f2; } hh;
    hh.s[0]=f2h(o.x); hh.s[1]=f2h(o.y); hh.s[2]=f2h(o.z); hh.s[3]=f2h(o.w);
    ((float2*)(oh + (size_t)row * HID))[threadIdx.x] = hh.f2;
}

// plain rmsnorm for final output
__global__ __launch_bounds__(256) void rmsnorm_kernel(const float* __restrict__ x,
                                                      const float* __restrict__ w,
                                                      float* __restrict__ out) {
    int row = blockIdx.x;
    const float4* xr = (const float4*)(x + (size_t)row * HID);
    float4 xv = xr[threadIdx.x];
    float ss = xv.x*xv.x + xv.y*xv.y + xv.z*xv.z + xv.w*xv.w;
    for (int off = 32; off; off >>= 1) ss += __shfl_xor(ss, off);
    __shared__ float sred[4];
    if ((threadIdx.x & 63) == 0) sred[threadIdx.x >> 6] = ss;
    __syncthreads();
    float tot = sred[0] + sred[1] + sred[2] + sred[3];
    float scale = rsqrtf(tot * (1.0f / (float)HID) + 1e-5f);
    float4 wv = ((const float4*)w)[threadIdx.x];
    float4 o;
    o.x = xv.x * scale * wv.x; o.y = xv.y * scale * wv.y;
    o.z = xv.z * scale * wv.z; o.w = xv.w * scale * wv.w;
    ((float4*)(out + (size_t)row * HID))[threadIdx.x] = o;
}

// ---------------- RoPE apply ----------------
__global__ void rope_apply_kernel(float* __restrict__ p, const float* __restrict__ cosb,
                                  const float* __restrict__ sinb, int nh, int total) {
    int gid = blockIdx.x * 256 + threadIdx.x;
    if (gid >= total) return;
    int per = nh * 32;
    int t = gid / per, r = gid % per;
    int hh = r >> 5, i = r & 31;
    float c = cosb[t*32 + i], s = sinb[t*32 + i];
    float* base = p + (size_t)t * (nh * HD) + hh * HD + i;
    float a = base[0], b = base[32];
    base[0]  = a * c - b * s;
    base[32] = b * c + a * s;
}

// ---------------- single-pass fp16 128x128 GEMM core ----------------
__device__ __forceinline__ void gemm128_core(
        const short* pA0, const short* pA1, const short* pB0, const short* pB1,
        int Kd, int tid, short* As, short* Bs, f32x4 (&acc)[4][4]) {
    const int lane = tid & 63, lo = lane & 15, hi = lane >> 4;
    const int wid = tid >> 6, wr = wid >> 1, wc = wid & 1;
    const int srow = tid >> 2, scol = (tid & 3) * 8;
    for (int k0 = 0; k0 < Kd; k0 += 32) {
        s16x8 a0 = *(const s16x8*)(pA0 + k0);
        s16x8 a1 = *(const s16x8*)(pA1 + k0);
        s16x8 b0 = *(const s16x8*)(pB0 + k0);
        s16x8 b1 = *(const s16x8*)(pB1 + k0);
        __syncthreads();
        *(s16x8*)&As[srow*40 + scol] = a0;
        *(s16x8*)&As[(64+srow)*40 + scol] = a1;
        *(s16x8*)&Bs[srow*40 + scol] = b0;
        *(s16x8*)&Bs[(64+srow)*40 + scol] = b1;
        __syncthreads();
        f16x8 aF[4], bF[4];
        #pragma unroll
        for (int m = 0; m < 4; ++m) aF[m] = *(const f16x8*)&As[(wr*64 + m*16 + lo)*40 + hi*8];
        #pragma unroll
        for (int n = 0; n < 4; ++n) bF[n] = *(const f16x8*)&Bs[(wc*64 + n*16 + lo)*40 + hi*8];
        #pragma unroll
        for (int m = 0; m < 4; ++m)
            #pragma unroll
            for (int n = 0; n < 4; ++n)
                acc[m][n] = __builtin_amdgcn_mfma_f32_16x16x32_f16(aF[m], bF[n], acc[m][n], 0, 0, 0);
    }
}

// ---------------- generic fp16 GEMM: C = A@B^T (+resid) ----------------
__global__ __launch_bounds__(256) void gemm_h16_kernel(const short* __restrict__ Ag,
        const short* __restrict__ Bg, float* __restrict__ C,
        const float* __restrict__ resid, int N, int Kd) {
    __shared__ __align__(16) short As[128*40], Bs[128*40];
    const int tid = threadIdx.x;
    const int lane = tid & 63, lo = lane & 15, hi = lane >> 4;
    const int wid = tid >> 6, wr = wid >> 1, wc = wid & 1;
    const int m0 = blockIdx.y * 128, n0 = blockIdx.x * 128;
    const int srow = tid >> 2, scol = (tid & 3) * 8;
    f32x4 acc[4][4];
    #pragma unroll
    for (int m = 0; m < 4; ++m)
        #pragma unroll
        for (int n = 0; n < 4; ++n) { acc[m][n][0]=0.f; acc[m][n][1]=0.f; acc[m][n][2]=0.f; acc[m][n][3]=0.f; }
    gemm128_core(Ag + (size_t)(m0+srow)*Kd + scol, Ag + (size_t)(m0+64+srow)*Kd + scol,
                 Bg + (size_t)(n0+srow)*Kd + scol, Bg + (size_t)(n0+64+srow)*Kd + scol,
                 Kd, tid, As, Bs, acc);
    #pragma unroll
    for (int m = 0; m < 4; ++m)
        #pragma unroll
        for (int n = 0; n < 4; ++n)
            #pragma unroll
            for (int r = 0; r < 4; ++r) {
                int row = m0 + wr*64 + m*16 + hi*4 + r;
                int col = n0 + wc*64 + n*16 + lo;
                float val = acc[m][n][r];
                if (resid) val += resid[(size_t)row * N + col];
                C[(size_t)row * N + col] = val;
            }
}

// ---------------- fused QKV GEMM (fp16) ----------------
__global__ __launch_bounds__(256) void qkv_h16_kernel(const short* __restrict__ Xh,
        const short* __restrict__ qw16, const short* __restrict__ kw16,
        const short* __restrict__ vw16,
        float* __restrict__ qo, float* __restrict__ ko, float* __restrict__ vo) {
    __shared__ __align__(16) short As[128*40], Bs[128*40];
    const int bx = blockIdx.x;
    const short* Bp; float* Cp; int Nc, n0;
    if (bx < 8)       { Bp = qw16; Cp = qo; Nc = 1024; n0 = bx * 128; }
    else if (bx < 10) { Bp = kw16; Cp = ko; Nc = 256;  n0 = (bx - 8) * 128; }
    else              { Bp = vw16; Cp = vo; Nc = 256;  n0 = (bx - 10) * 128; }
    const int tid = threadIdx.x;
    const int lane = tid & 63, lo = lane & 15, hi = lane >> 4;
    const int wid = tid >> 6, wr = wid >> 1, wc = wid & 1;
    const int m0 = blockIdx.y * 128;
    const int srow = tid >> 2, scol = (tid & 3) * 8;
    f32x4 acc[4][4];
    #pragma unroll
    for (int m = 0; m < 4; ++m)
        #pragma unroll
        for (int n = 0; n < 4; ++n) { acc[m][n][0]=0.f; acc[m][n][1]=0.f; acc[m][n][2]=0.f; acc[m][n][3]=0.f; }
    gemm128_core(Xh + (size_t)(m0+srow)*HID + scol, Xh + (size_t)(m0+64+srow)*HID + scol,
                 Bp + (size_t)(n0+srow)*HID + scol, Bp + (size_t)(n0+64+srow)*HID + scol,
                 HID, tid, As, Bs, acc);
    #pragma unroll
    for (int m = 0; m < 4; ++m)
        #pragma unroll
        for (int n = 0; n < 4; ++n)
            #pragma unroll
            for (int r = 0; r < 4; ++r) {
                int row = m0 + wr*64 + m*16 + hi*4 + r;
                int col = n0 + wc*64 + n*16 + lo;
                Cp[(size_t)row * Nc + col] = acc[m][n][r];
            }
}

// ---------------- fp16 MFMA flash attention; epilogue writes fp16 ----------------
__global__ __launch_bounds__(256) void attn_mfma_kernel(const float* __restrict__ q,
                                                        const float* __restrict__ k,
                                                        const float* __restrict__ v,
                                                        short* __restrict__ aoh) {
    __shared__ __align__(16) short Ks[64][72];
    __shared__ __align__(16) short Vt[64][72];
    __shared__ __align__(16) short Ps[4][16][72];
    const int wid = threadIdx.x >> 6, lane = threadIdx.x & 63;
    const int lo = lane & 15, hi = lane >> 4;
    const int head = blockIdx.x >> 5;
    const int qi = blockIdx.x & 31;
    const int q0 = (31 - qi) * 64;
    const int kvh = head >> 2;

    f16x8 qf[2];
    {
        const float* qr = q + (size_t)(q0 + wid*16 + lo) * HID + head*HD;
        #pragma unroll
        for (int kk = 0; kk < 2; ++kk)
            #pragma unroll
            for (int i = 0; i < 8; ++i)
                qf[kk][i] = (_Float16)qr[kk*32 + hi*8 + i];
    }

    f32x4 acc[4];
    float m[4], l[4];
    #pragma unroll
    for (int r = 0; r < 4; ++r) {
        m[r] = -1e30f; l[r] = 0.f;
        acc[0][r] = 0.f; acc[1][r] = 0.f; acc[2][r] = 0.f; acc[3][r] = 0.f;
    }

    const int ntiles = q0/64 + 1;
    const int skey = threadIdx.x >> 2;
    const int sdg  = (threadIdx.x & 3) * 16;

    for (int t = 0; t < ntiles; ++t) {
        const int k0 = t * 64;
        __syncthreads();
        {
            const float* kr = k + (size_t)(k0 + skey)*(KVH*HD) + kvh*HD + sdg;
            float4 a0 = ((const float4*)kr)[0], a1 = ((const float4*)kr)[1],
                   a2 = ((const float4*)kr)[2], a3 = ((const float4*)kr)[3];
            *(s16x8*)&Ks[skey][sdg]     = cvt8(a0, a1);
            *(s16x8*)&Ks[skey][sdg + 8] = cvt8(a2, a3);
            const float* vr = v + (size_t)(k0 + skey)*(KVH*HD) + kvh*HD + sdg;
            float4 b0 = ((const float4*)vr)[0], b1 = ((const float4*)vr)[1],
                   b2 = ((const float4*)vr)[2], b3 = ((const float4*)vr)[3];
            Vt[sdg+ 0][skey]=f2h(b0.x); Vt[sdg+ 1][skey]=f2h(b0.y);
            Vt[sdg+ 2][skey]=f2h(b0.z); Vt[sdg+ 3][skey]=f2h(b0.w);
            Vt[sdg+ 4][skey]=f2h(b1.x); Vt[sdg+ 5][skey]=f2h(b1.y);
            Vt[sdg+ 6][skey]=f2h(b1.z); Vt[sdg+ 7][skey]=f2h(b1.w);
            Vt[sdg+ 8][skey]=f2h(b2.x); Vt[sdg+ 9][skey]=f2h(b2.y);
            Vt[sdg+10][skey]=f2h(b2.z); Vt[sdg+11][skey]=f2h(b2.w);
            Vt[sdg+12][skey]=f2h(b3.x); Vt[sdg+13][skey]=f2h(b3.y);
            Vt[sdg+14][skey]=f2h(b3.z); Vt[sdg+15][skey]=f2h(b3.w);
        }
        __syncthreads();
        f32x4 s[4];
        #pragma unroll
        for (int f = 0; f < 4; ++f) {
            f32x4 sf; sf[0]=0.f; sf[1]=0.f; sf[2]=0.f; sf[3]=0.f;
            f16x8 bk0 = *(const f16x8*)&Ks[f*16 + lo][hi*8];
            sf = __builtin_amdgcn_mfma_f32_16x16x32_f16(qf[0], bk0, sf, 0, 0, 0);
            f16x8 bk1 = *(const f16x8*)&Ks[f*16 + lo][32 + hi*8];
            sf = __builtin_amdgcn_mfma_f32_16x16x32_f16(qf[1], bk1, sf, 0, 0, 0);
            s[f] = sf;
        }
        #pragma unroll
        for (int f = 0; f < 4; ++f)
            #pragma unroll
            for (int r = 0; r < 4; ++r) s[f][r] *= 0.125f;
        if (t == ntiles - 1) {
            int qrow = q0 + wid*16 + hi*4;
            #pragma unroll
            for (int f = 0; f < 4; ++f)
                #pragma unroll
                for (int r = 0; r < 4; ++r)
                    if (k0 + f*16 + lo > qrow + r) s[f][r] = -1e30f;
        }
        float sc_[4];
        #pragma unroll
        for (int r = 0; r < 4; ++r) {
            float x = fmaxf(fmaxf(s[0][r], s[1][r]), fmaxf(s[2][r], s[3][r]));
            x = fmaxf(x, __shfl_xor(x, 1));
            x = fmaxf(x, __shfl_xor(x, 2));
            x = fmaxf(x, __shfl_xor(x, 4));
            x = fmaxf(x, __shfl_xor(x, 8));
            float mn = fmaxf(m[r], x);
            sc_[r] = __expf(m[r] - mn);
            m[r] = mn;
            l[r] *= sc_[r];
            acc[0][r] *= sc_[r]; acc[1][r] *= sc_[r];
            acc[2][r] *= sc_[r]; acc[3][r] *= sc_[r];
        }
        float rs[4] = {0.f, 0.f, 0.f, 0.f};
        #pragma unroll
        for (int f = 0; f < 4; ++f)
            #pragma unroll
            for (int r = 0; r < 4; ++r) {
                float e = __expf(s[f][r] - m[r]);
                rs[r] += e;
                Ps[wid][hi*4 + r][f*16 + lo] = f2h(e);
            }
        #pragma unroll
        for (int r = 0; r < 4; ++r) {
            float x = rs[r];
            x += __shfl_xor(x, 1); x += __shfl_xor(x, 2);
            x += __shfl_xor(x, 4); x += __shfl_xor(x, 8);
            l[r] += x;
        }
        asm volatile("s_waitcnt lgkmcnt(0)" ::: "memory");
        __builtin_amdgcn_sched_barrier(0);
        f16x8 pa0 = *(const f16x8*)&Ps[wid][lo][hi*8];
        f16x8 pa1 = *(const f16x8*)&Ps[wid][lo][32 + hi*8];
        #pragma unroll
        for (int f = 0; f < 4; ++f) {
            f32x4 o = acc[f];
            f16x8 v0 = *(const f16x8*)&Vt[f*16 + lo][hi*8];
            o = __builtin_amdgcn_mfma_f32_16x16x32_f16(pa0, v0, o, 0, 0, 0);
            f16x8 v1 = *(const f16x8*)&Vt[f*16 + lo][32 + hi*8];
            o = __builtin_amdgcn_mfma_f32_16x16x32_f16(pa1, v1, o, 0, 0, 0);
            acc[f] = o;
        }
    }
    #pragma unroll
    for (int r = 0; r < 4; ++r) {
        float inv = 1.0f / l[r];
        #pragma unroll
        for (int f = 0; f < 4; ++f) {
            size_t o = (size_t)(q0 + wid*16 + hi*4 + r) * HID + head*HD + f*16 + lo;
            aoh[o] = f2h(acc[f][r] * inv);
        }
    }
}

// ---------------- gate + top-2 routing (exact fp32) ----------------
__global__ __launch_bounds__(64) void gate_topk_kernel(const float* __restrict__ xn,
                                                       const float* __restrict__ gw,
                                                       int* __restrict__ cnt,
                                                       int* __restrict__ idx,
                                                       float* __restrict__ wt) {
    int t = blockIdx.x, lane = threadIdx.x;
    float acc[NE] = {};
    for (int i = lane; i < HID; i += 64) {
        float x = xn[(size_t)t * HID + i];
        #pragma unroll
        for (int e = 0; e < NE; ++e) acc[e] += x * gw[e * HID + i];
    }
    #pragma unroll
    for (int e = 0; e < NE; ++e)
        for (int off = 32; off; off >>= 1) acc[e] += __shfl_xor(acc[e], off);
    if (lane == 0) {
        float mx = acc[0];
        #pragma unroll
        for (int e = 1; e < NE; ++e) mx = fmaxf(mx, acc[e]);
        float p[NE];
        #pragma unroll
        for (int e = 0; e < NE; ++e) p[e] = __expf(acc[e] - mx);
        int i0 = 0;
        #pragma unroll
        for (int e = 1; e < NE; ++e) if (p[e] > p[i0]) i0 = e;
        int i1 = -1;
        #pragma unroll
        for (int e = 0; e < NE; ++e) if (e != i0 && (i1 < 0 || p[e] > p[i1])) i1 = e;
        float w0 = p[i0], w1 = p[i1];
        float inv = 1.0f / (w0 + w1);
        int s0 = atomicAdd(&cnt[i0], 1);
        idx[i0 * S_LEN + s0] = t; wt[i0 * S_LEN + s0] = w0 * inv;
        int s1 = atomicAdd(&cnt[i1], 1);
        idx[i1 * S_LEN + s1] = t; wt[i1 * S_LEN + s1] = w1 * inv;
    }
}

// ---------------- MoE mlp1 (fp16): ab16 = fp16( silu(x@w1^T) * (x@w3^T) ) ----------------
__global__ __launch_bounds__(256) void moe_mlp1_h16(const short* __restrict__ Xh,
        const short* __restrict__ W1h, const short* __restrict__ W3h,
        const int* __restrict__ cnt, const int* __restrict__ idx,
        short* __restrict__ abh) {
    int e = blockIdx.z;
    int ne = cnt[e];
    int m0 = blockIdx.y * 128;
    if (m0 >= ne) return;
    int f0 = blockIdx.x * 64;
    __shared__ __align__(16) short As[128*40];
    __shared__ __align__(16) short Gs[64*40], Us[64*40];
    __shared__ int rows[128];
    const int tid = threadIdx.x;
    if (tid < 128) {
        int slot = m0 + tid;
        rows[tid] = (slot < ne) ? idx[e * S_LEN + slot] : 0;
    }
    __syncthreads();
    const int lane = tid & 63, lo = lane & 15, hi = lane >> 4;
    const int wid = tid >> 6, wr = wid >> 1, wc = wid & 1;
    const int srow = tid >> 2, scol = (tid & 3) * 8;
    const short* pX0 = Xh + (size_t)rows[srow] * HID + scol;
    const short* pX1 = Xh + (size_t)rows[64 + srow] * HID + scol;
    const short* p1 = W1h + ((size_t)e * FF + f0 + srow) * HID + scol;
    const short* p3 = W3h + ((size_t)e * FF + f0 + srow) * HID + scol;

    f32x4 ag[4][2], au[4][2];
    #pragma unroll
    for (int m = 0; m < 4; ++m)
        #pragma unroll
        for (int n = 0; n < 2; ++n) {
            ag[m][n][0]=0.f; ag[m][n][1]=0.f; ag[m][n][2]=0.f; ag[m][n][3]=0.f;
            au[m][n][0]=0.f; au[m][n][1]=0.f; au[m][n][2]=0.f; au[m][n][3]=0.f;
        }

    for (int k0 = 0; k0 < HID; k0 += 32) {
        s16x8 a0 = *(const s16x8*)(pX0 + k0);
        s16x8 a1 = *(const s16x8*)(pX1 + k0);
        s16x8 g0 = *(const s16x8*)(p1 + k0);
        s16x8 u0 = *(const s16x8*)(p3 + k0);
        __syncthreads();
        *(s16x8*)&As[srow*40 + scol] = a0;
        *(s16x8*)&As[(64+srow)*40 + scol] = a1;
        *(s16x8*)&Gs[srow*40 + scol] = g0;
        *(s16x8*)&Us[srow*40 + scol] = u0;
        __syncthreads();
        f16x8 aF[4], gF[2], uF[2];
        #pragma unroll
        for (int m = 0; m < 4; ++m) aF[m] = *(const f16x8*)&As[(wr*64 + m*16 + lo)*40 + hi*8];
        #pragma unroll
        for (int n = 0; n < 2; ++n) {
            gF[n] = *(const f16x8*)&Gs[(wc*32 + n*16 + lo)*40 + hi*8];
            uF[n] = *(const f16x8*)&Us[(wc*32 + n*16 + lo)*40 + hi*8];
        }
        #pragma unroll
        for (int m = 0; m < 4; ++m)
            #pragma unroll
            for (int n = 0; n < 2; ++n) {
                ag[m][n] = __builtin_amdgcn_mfma_f32_16x16x32_f16(aF[m], gF[n], ag[m][n], 0, 0, 0);
                au[m][n] = __builtin_amdgcn_mfma_f32_16x16x32_f16(aF[m], uF[n], au[m][n], 0, 0, 0);
            }
    }
    #pragma unroll
    for (int m = 0; m < 4; ++m)
        #pragma unroll
        for (int n = 0; n < 2; ++n)
            #pragma unroll
            for (int r = 0; r < 4; ++r) {
                int slot = m0 + wr*64 + m*16 + hi*4 + r;
                if (slot >= ne) continue;
                float g = ag[m][n][r], u = au[m][n][r];
                float a = g * (1.0f / (1.0f + __expf(-g))) * u;
                abh[((size_t)e * S_LEN + slot) * FF + f0 + wc*32 + n*16 + lo] = f2h(a);
            }
}

// ---------------- MoE mlp2 (fp16): h += wt * (a @ w2^T) ----------------
__global__ __launch_bounds__(256) void moe_mlp2_h16(const short* __restrict__ abh,
        const short* __restrict__ W2h,
        const int* __restrict__ cnt, const int* __restrict__ idx,
        const float* __restrict__ wt, float* __restrict__ hbuf) {
    int e = blockIdx.z;
    int ne = cnt[e];
    int m0 = blockIdx.y * 128;
    if (m0 >= ne) return;
    int n0 = blockIdx.x * 128;
    __shared__ __align__(16) short As[128*40], Bs[128*40];
    const int tid = threadIdx.x;
    const int lane = tid & 63, lo = lane & 15, hi = lane >> 4;
    const int wid = tid >> 6, wr = wid >> 1, wc = wid & 1;
    const int srow = tid >> 2, scol = (tid & 3) * 8;
    f32x4 acc[4][4];
    #pragma unroll
    for (int m = 0; m < 4; ++m)
        #pragma unroll
        for (int n = 0; n < 4; ++n) { acc[m][n][0]=0.f; acc[m][n][1]=0.f; acc[m][n][2]=0.f; acc[m][n][3]=0.f; }
    gemm128_core(abh + ((size_t)e*S_LEN + m0 + srow)*FF + scol,
                 abh + ((size_t)e*S_LEN + m0 + 64 + srow)*FF + scol,
                 W2h + ((size_t)e*HID + n0 + srow)*FF + scol,
                 W2h + ((size_t)e*HID + n0 + 64 + srow)*FF + scol,
                 FF, tid, As, Bs, acc);
    #pragma unroll
    for (int m = 0; m < 4; ++m) {
        #pragma unroll
        for (int r = 0; r < 4; ++r) {
            int slot = m0 + wr*64 + m*16 + hi*4 + r;
            if (slot >= ne) continue;
            int tok = idx[e * S_LEN + slot];
            float wv = wt[e * S_LEN + slot];
            #pragma unroll
            for (int n = 0; n < 4; ++n)
                atomicAdd(&hbuf[(size_t)tok * HID + n0 + wc*64 + n*16 + lo], acc[m][n][r] * wv);
        }
    }
}

extern "C" void kernel_launch(void* const* d_in, const int* in_sizes, int n_in,
                              void* d_out, int out_size, void* d_ws, size_t ws_size,
                              hipStream_t stream) {
    const float* emb = (const float*)d_in[0];
    const float* ln1 = (const float*)d_in[1];
    const float* ln2 = (const float*)d_in[2];
    const float* fln = (const float*)d_in[3];
    const float* qw  = (const float*)d_in[4];
    const float* kw  = (const float*)d_in[5];
    const float* vw  = (const float*)d_in[6];
    const float* ow  = (const float*)d_in[7];
    const float* gw  = (const float*)d_in[8];
    const float* w1  = (const float*)d_in[9];
    const float* w2  = (const float*)d_in[10];
    const float* w3  = (const float*)d_in[11];

    float* ws   = (float*)d_ws;
    float* h    = ws + OFF_H;
    float* xn   = ws + OFF_XN;
    float* q    = ws + OFF_Q;
    float* kb   = ws + OFF_K;
    float* vb   = ws + OFF_V;
    float* cosb = ws + OFF_COS;
    float* sinb = ws + OFF_SIN;
    float* wt   = ws + OFF_WT;
    int*   cnt  = (int*)(ws + OFF_INT);
    int*   idx  = cnt + 8;
    short* xh   = (short*)(ws + OFF_XH);
    short* aoh  = (short*)(ws + OFF_AOH);
    short* abh  = (short*)(ws + OFF_ABH);
    short* WC   = (short*)(ws + OFF_WCVT);

    // converted weights (fp16), non-overlapping
    short* sq = WC;
    short* sk = sq + HID*HID;
    short* sv = sk + KVH*HD*HID;
    short* so = sv + KVH*HD*HID;
    short* s1 = so + HID*HID;
    short* s3 = s1 + (size_t)NE*FF*HID;
    short* s2 = s3 + (size_t)NE*FF*HID;

    hipMemcpyAsync(h, emb, (size_t)S_LEN * HID * sizeof(float), hipMemcpyDeviceToDevice, stream);
    rope_tables_kernel<<<S_LEN * 32 / 256, 256, 0, stream>>>(cosb, sinb);

    const int n8_qo = HID*HID/8, n8_kv = KVH*HD*HID/8, n8_w = NE*FF*HID/8;

    for (int l = 0; l < NL; ++l) {
        cvt16_kernel<<<n8_qo/256, 256, 0, stream>>>(qw + (size_t)l*HID*HID, sq, n8_qo);
        cvt16_kernel<<<n8_kv/256, 256, 0, stream>>>(kw + (size_t)l*KVH*HD*HID, sk, n8_kv);
        cvt16_kernel<<<n8_kv/256, 256, 0, stream>>>(vw + (size_t)l*KVH*HD*HID, sv, n8_kv);
        cvt16_kernel<<<n8_qo/256, 256, 0, stream>>>(ow + (size_t)l*HID*HID, so, n8_qo);

        rmsnorm_h16_kernel<<<S_LEN, 256, 0, stream>>>(h, ln1 + l * HID, xn, xh);
        qkv_h16_kernel<<<dim3(12, 16), 256, 0, stream>>>(xh, sq, sk, sv, q, kb, vb);
        rope_apply_kernel<<<(S_LEN * NHEAD * 32) / 256, 256, 0, stream>>>(q, cosb, sinb, NHEAD, S_LEN * NHEAD * 32);
        rope_apply_kernel<<<(S_LEN * KVH * 32) / 256, 256, 0, stream>>>(kb, cosb, sinb, KVH, S_LEN * KVH * 32);
        attn_mfma_kernel<<<NHEAD * 32, 256, 0, stream>>>(q, kb, vb, aoh);
        gemm_h16_kernel<<<dim3(8, 16), 256, 0, stream>>>(aoh, so, h, h, HID, HID);

        rmsnorm_h16_kernel<<<S_LEN, 256, 0, stream>>>(h, ln2 + l * HID, xn, xh);
        hipMemsetAsync(cnt, 0, 8 * sizeof(int), stream);
        gate_topk_kernel<<<S_LEN, 64, 0, stream>>>(xn, gw + (size_t)l * NE * HID, cnt, idx, wt);

        cvt16_kernel<<<n8_w/256, 256, 0, stream>>>(w1 + (size_t)l*NE*FF*HID, s1, n8_w);
        cvt16_kernel<<<n8_w/256, 256, 0, stream>>>(w3 + (size_t)l*NE*FF*HID, s3, n8_w);
        moe_mlp1_h16<<<dim3(16, 16, 8), 256, 0, stream>>>(xh, s1, s3, cnt, idx, abh);

        cvt16_kernel<<<n8_w/256, 256, 0, stream>>>(w2 + (size_t)l*NE*HID*FF, s2, n8_w);
        moe_mlp2_h16<<<dim3(8, 16, 8), 256, 0, stream>>>(abh, s2, cnt, idx, wt, h);
    }
    rmsnorm_kernel<<<S_LEN, 256, 0, stream>>>(h, fln, (float*)d_out);
}

// Round 7
// 664.333 us; speedup vs baseline: 6.8877x; 1.0792x over previous
//
#include <hip/hip_runtime.h>
#include <hip/hip_bf16.h>
#include <math.h>

#define S_LEN 2048
#define HID   1024
#define NHEAD 16
#define KVH   4
#define HD    64
#define FF    1024
#define NE    8
#define NL    2

// ---- workspace layout (float offsets) ----
#define OFF_H    0
#define OFF_XN   (OFF_H + S_LEN*HID)
#define OFF_Q    (OFF_XN + S_LEN*HID)
#define OFF_K    (OFF_Q + S_LEN*HID)
#define OFF_V    (OFF_K + S_LEN*KVH*HD)
#define OFF_COS  (OFF_V + S_LEN*KVH*HD)
#define OFF_SIN  (OFF_COS + S_LEN*32)
#define OFF_WT   (OFF_SIN + S_LEN*32)
#define OFF_INT  (OFF_WT + NE*S_LEN)
#define OFF_XH   (OFF_INT + NE*S_LEN + 16)
#define OFF_AOH  (OFF_XH + S_LEN*HID/2)
#define OFF_ABH  (OFF_AOH + S_LEN*HID/2)
#define OFF_PO   (OFF_ABH + NE*S_LEN*FF/2)
#define OFF_PM   (OFF_PO + 80*NHEAD*64*64)
#define OFF_PL   (OFF_PM + 80*NHEAD*64)
#define OFF_WCVT (OFF_PL + 80*NHEAD*64)
// WCVT region (shorts): qkvo 2.5M + w1 8M + w3 8M + w2 8M = 26.5M shorts = 53MB

typedef __attribute__((ext_vector_type(8))) _Float16 f16x8;
typedef __attribute__((ext_vector_type(8))) short  s16x8;
typedef __attribute__((ext_vector_type(4))) float  f32x4;

__device__ __forceinline__ short f2h(float f) {
    union { _Float16 h; short s; } u;
    u.h = (_Float16)f;
    return u.s;
}

__device__ __forceinline__ s16x8 cvt8(float4 a, float4 b) {
    s16x8 w;
    w[0]=f2h(a.x); w[1]=f2h(a.y); w[2]=f2h(a.z); w[3]=f2h(a.w);
    w[4]=f2h(b.x); w[5]=f2h(b.y); w[6]=f2h(b.z); w[7]=f2h(b.w);
    return w;
}

// ---------------- fp32 -> fp16 convert ----------------
__global__ __launch_bounds__(256) void cvt16_kernel(const float* __restrict__ src,
                                                    short* __restrict__ dst, int n8) {
    int gid = blockIdx.x * 256 + threadIdx.x;
    if (gid >= n8) return;
    const float4* s = (const float4*)src + (size_t)gid * 2;
    *(s16x8*)(dst + (size_t)gid * 8) = cvt8(s[0], s[1]);
}

// ---------------- RoPE tables ----------------
__global__ void rope_tables_kernel(float* __restrict__ cosb, float* __restrict__ sinb) {
    int gid = blockIdx.x * 256 + threadIdx.x;
    int t = gid >> 5, i = gid & 31;
    float invf = powf(1.0e6f, -(float)i / 32.0f);
    float ang = (float)t * invf;
    cosb[gid] = cosf(ang);
    sinb[gid] = sinf(ang);
}

// ---------------- RMSNorm -> fp32 + fp16 ----------------
__global__ __launch_bounds__(256) void rmsnorm_h16_kernel(const float* __restrict__ x,
                                                          const float* __restrict__ w,
                                                          float* __restrict__ out,
                                                          short* __restrict__ oh) {
    int row = blockIdx.x;
    const float4* xr = (const float4*)(x + (size_t)row * HID);
    float4 xv = xr[threadIdx.x];
    float ss = xv.x*xv.x + xv.y*xv.y + xv.z*xv.z + xv.w*xv.w;
    for (int off = 32; off; off >>= 1) ss += __shfl_xor(ss, off);
    __shared__ float sred[4];
    if ((threadIdx.x & 63) == 0) sred[threadIdx.x >> 6] = ss;
    __syncthreads();
    float tot = sred[0] + sred[1] + sred[2] + sred[3];
    float scale = rsqrtf(tot * (1.0f / (float)HID) + 1e-5f);
    float4 wv = ((const float4*)w)[threadIdx.x];
    float4 o;
    o.x = xv.x * scale * wv.x; o.y = xv.y * scale * wv.y;
    o.z = xv.z * scale * wv.z; o.w = xv.w * scale * wv.w;
    ((float4*)(out + (size_t)row * HID))[threadIdx.x] = o;
    union { short s[4]; float2 f2; } hh;
    hh.s[0]=f2h(o.x); hh.s[1]=f2h(o.y); hh.s[2]=f2h(o.z); hh.s[3]=f2h(o.w);
    ((float2*)(oh + (size_t)row * HID))[threadIdx.x] = hh.f2;
}

// plain rmsnorm for final output
__global__ __launch_bounds__(256) void rmsnorm_kernel(const float* __restrict__ x,
                                                      const float* __restrict__ w,
                                                      float* __restrict__ out) {
    int row = blockIdx.x;
    const float4* xr = (const float4*)(x + (size_t)row * HID);
    float4 xv = xr[threadIdx.x];
    float ss = xv.x*xv.x + xv.y*xv.y + xv.z*xv.z + xv.w*xv.w;
    for (int off = 32; off; off >>= 1) ss += __shfl_xor(ss, off);
    __shared__ float sred[4];
    if ((threadIdx.x & 63) == 0) sred[threadIdx.x >> 6] = ss;
    __syncthreads();
    float tot = sred[0] + sred[1] + sred[2] + sred[3];
    float scale = rsqrtf(tot * (1.0f / (float)HID) + 1e-5f);
    float4 wv = ((const float4*)w)[threadIdx.x];
    float4 o;
    o.x = xv.x * scale * wv.x; o.y = xv.y * scale * wv.y;
    o.z = xv.z * scale * wv.z; o.w = xv.w * scale * wv.w;
    ((float4*)(out + (size_t)row * HID))[threadIdx.x] = o;
}

// ---------------- RoPE apply ----------------
__global__ void rope_apply_kernel(float* __restrict__ p, const float* __restrict__ cosb,
                                  const float* __restrict__ sinb, int nh, int total) {
    int gid = blockIdx.x * 256 + threadIdx.x;
    if (gid >= total) return;
    int per = nh * 32;
    int t = gid / per, r = gid % per;
    int hh = r >> 5, i = r & 31;
    float c = cosb[t*32 + i], s = sinb[t*32 + i];
    float* base = p + (size_t)t * (nh * HD) + hh * HD + i;
    float a = base[0], b = base[32];
    base[0]  = a * c - b * s;
    base[32] = b * c + a * s;
}

// ---------------- single-pass fp16 128x128 GEMM core ----------------
__device__ __forceinline__ void gemm128_core(
        const short* pA0, const short* pA1, const short* pB0, const short* pB1,
        int Kd, int tid, short* As, short* Bs, f32x4 (&acc)[4][4]) {
    const int lane = tid & 63, lo = lane & 15, hi = lane >> 4;
    const int wid = tid >> 6, wr = wid >> 1, wc = wid & 1;
    const int srow = tid >> 2, scol = (tid & 3) * 8;
    for (int k0 = 0; k0 < Kd; k0 += 32) {
        s16x8 a0 = *(const s16x8*)(pA0 + k0);
        s16x8 a1 = *(const s16x8*)(pA1 + k0);
        s16x8 b0 = *(const s16x8*)(pB0 + k0);
        s16x8 b1 = *(const s16x8*)(pB1 + k0);
        __syncthreads();
        *(s16x8*)&As[srow*40 + scol] = a0;
        *(s16x8*)&As[(64+srow)*40 + scol] = a1;
        *(s16x8*)&Bs[srow*40 + scol] = b0;
        *(s16x8*)&Bs[(64+srow)*40 + scol] = b1;
        __syncthreads();
        f16x8 aF[4], bF[4];
        #pragma unroll
        for (int m = 0; m < 4; ++m) aF[m] = *(const f16x8*)&As[(wr*64 + m*16 + lo)*40 + hi*8];
        #pragma unroll
        for (int n = 0; n < 4; ++n) bF[n] = *(const f16x8*)&Bs[(wc*64 + n*16 + lo)*40 + hi*8];
        #pragma unroll
        for (int m = 0; m < 4; ++m)
            #pragma unroll
            for (int n = 0; n < 4; ++n)
                acc[m][n] = __builtin_amdgcn_mfma_f32_16x16x32_f16(aF[m], bF[n], acc[m][n], 0, 0, 0);
    }
}

// ---------------- generic fp16 GEMM: C = A@B^T (+resid) ----------------
__global__ __launch_bounds__(256) void gemm_h16_kernel(const short* __restrict__ Ag,
        const short* __restrict__ Bg, float* __restrict__ C,
        const float* __restrict__ resid, int N, int Kd) {
    __shared__ __align__(16) short As[128*40], Bs[128*40];
    const int tid = threadIdx.x;
    const int lane = tid & 63, lo = lane & 15, hi = lane >> 4;
    const int wid = tid >> 6, wr = wid >> 1, wc = wid & 1;
    const int m0 = blockIdx.y * 128, n0 = blockIdx.x * 128;
    const int srow = tid >> 2, scol = (tid & 3) * 8;
    f32x4 acc[4][4];
    #pragma unroll
    for (int m = 0; m < 4; ++m)
        #pragma unroll
        for (int n = 0; n < 4; ++n) { acc[m][n][0]=0.f; acc[m][n][1]=0.f; acc[m][n][2]=0.f; acc[m][n][3]=0.f; }
    gemm128_core(Ag + (size_t)(m0+srow)*Kd + scol, Ag + (size_t)(m0+64+srow)*Kd + scol,
                 Bg + (size_t)(n0+srow)*Kd + scol, Bg + (size_t)(n0+64+srow)*Kd + scol,
                 Kd, tid, As, Bs, acc);
    #pragma unroll
    for (int m = 0; m < 4; ++m)
        #pragma unroll
        for (int n = 0; n < 4; ++n)
            #pragma unroll
            for (int r = 0; r < 4; ++r) {
                int row = m0 + wr*64 + m*16 + hi*4 + r;
                int col = n0 + wc*64 + n*16 + lo;
                float val = acc[m][n][r];
                if (resid) val += resid[(size_t)row * N + col];
                C[(size_t)row * N + col] = val;
            }
}

// ---------------- fused QKV GEMM (fp16) ----------------
__global__ __launch_bounds__(256) void qkv_h16_kernel(const short* __restrict__ Xh,
        const short* __restrict__ qw16, const short* __restrict__ kw16,
        const short* __restrict__ vw16,
        float* __restrict__ qo, float* __restrict__ ko, float* __restrict__ vo) {
    __shared__ __align__(16) short As[128*40], Bs[128*40];
    const int bx = blockIdx.x;
    const short* Bp; float* Cp; int Nc, n0;
    if (bx < 8)       { Bp = qw16; Cp = qo; Nc = 1024; n0 = bx * 128; }
    else if (bx < 10) { Bp = kw16; Cp = ko; Nc = 256;  n0 = (bx - 8) * 128; }
    else              { Bp = vw16; Cp = vo; Nc = 256;  n0 = (bx - 10) * 128; }
    const int tid = threadIdx.x;
    const int lane = tid & 63, lo = lane & 15, hi = lane >> 4;
    const int wid = tid >> 6, wr = wid >> 1, wc = wid & 1;
    const int m0 = blockIdx.y * 128;
    const int srow = tid >> 2, scol = (tid & 3) * 8;
    f32x4 acc[4][4];
    #pragma unroll
    for (int m = 0; m < 4; ++m)
        #pragma unroll
        for (int n = 0; n < 4; ++n) { acc[m][n][0]=0.f; acc[m][n][1]=0.f; acc[m][n][2]=0.f; acc[m][n][3]=0.f; }
    gemm128_core(Xh + (size_t)(m0+srow)*HID + scol, Xh + (size_t)(m0+64+srow)*HID + scol,
                 Bp + (size_t)(n0+srow)*HID + scol, Bp + (size_t)(n0+64+srow)*HID + scol,
                 HID, tid, As, Bs, acc);
    #pragma unroll
    for (int m = 0; m < 4; ++m)
        #pragma unroll
        for (int n = 0; n < 4; ++n)
            #pragma unroll
            for (int r = 0; r < 4; ++r) {
                int row = m0 + wr*64 + m*16 + hi*4 + r;
                int col = n0 + wc*64 + n*16 + lo;
                Cp[(size_t)row * Nc + col] = acc[m][n][r];
            }
}

// ---------------- split-K fp16 MFMA flash attention -> partials ----------------
// grid (80, NHEAD): slot -> (q-tile, key-chunk of <=8 tiles). Long chunks first.
__global__ __launch_bounds__(256) void attn_mfma_kernel(const float* __restrict__ q,
                                                        const float* __restrict__ k,
                                                        const float* __restrict__ v,
                                                        float* __restrict__ pO,
                                                        float* __restrict__ pm,
                                                        float* __restrict__ pl) {
    __shared__ __align__(16) short Ks[64][72];
    __shared__ __align__(16) short Vt[64][72];
    __shared__ __align__(16) short Ps[4][16][72];
    const int wid = threadIdx.x >> 6, lane = threadIdx.x & 63;
    const int lo = lane & 15, hi = lane >> 4;
    const int head = blockIdx.y;
    const int s = 79 - blockIdx.x;            // long chunks dispatched first
    int qi, c;
    if (s < 8)       { qi = s;                     c = 0; }
    else if (s < 24) { int t = s - 8;  qi = 8  + (t >> 1); c = t & 1; }
    else if (s < 48) { int t = s - 24; qi = 16 + t / 3;    c = t % 3; }
    else             { int t = s - 48; qi = 24 + (t >> 2); c = t & 3; }
    const int t_beg = c * 8;
    const int t_end = min(t_beg + 8, qi + 1);
    const int q0 = qi * 64;
    const int kvh = head >> 2;

    f16x8 qf[2];
    {
        const float* qr = q + (size_t)(q0 + wid*16 + lo) * HID + head*HD;
        #pragma unroll
        for (int kk = 0; kk < 2; ++kk)
            #pragma unroll
            for (int i = 0; i < 8; ++i)
                qf[kk][i] = (_Float16)qr[kk*32 + hi*8 + i];
    }

    f32x4 acc[4];
    float m[4], l[4];
    #pragma unroll
    for (int r = 0; r < 4; ++r) {
        m[r] = -1e30f; l[r] = 0.f;
        acc[0][r] = 0.f; acc[1][r] = 0.f; acc[2][r] = 0.f; acc[3][r] = 0.f;
    }

    const int skey = threadIdx.x >> 2;
    const int sdg  = (threadIdx.x & 3) * 16;

    // prefetch tile t_beg into registers
    float4 ka0, ka1, ka2, ka3, vv0, vv1, vv2, vv3;
    {
        const float* kr = k + (size_t)(t_beg*64 + skey)*(KVH*HD) + kvh*HD + sdg;
        ka0 = ((const float4*)kr)[0]; ka1 = ((const float4*)kr)[1];
        ka2 = ((const float4*)kr)[2]; ka3 = ((const float4*)kr)[3];
        const float* vr = v + (size_t)(t_beg*64 + skey)*(KVH*HD) + kvh*HD + sdg;
        vv0 = ((const float4*)vr)[0]; vv1 = ((const float4*)vr)[1];
        vv2 = ((const float4*)vr)[2]; vv3 = ((const float4*)vr)[3];
    }

    for (int t = t_beg; t < t_end; ++t) {
        __syncthreads();   // previous tile's LDS reads complete
        *(s16x8*)&Ks[skey][sdg]     = cvt8(ka0, ka1);
        *(s16x8*)&Ks[skey][sdg + 8] = cvt8(ka2, ka3);
        Vt[sdg+ 0][skey]=f2h(vv0.x); Vt[sdg+ 1][skey]=f2h(vv0.y);
        Vt[sdg+ 2][skey]=f2h(vv0.z); Vt[sdg+ 3][skey]=f2h(vv0.w);
        Vt[sdg+ 4][skey]=f2h(vv1.x); Vt[sdg+ 5][skey]=f2h(vv1.y);
        Vt[sdg+ 6][skey]=f2h(vv1.z); Vt[sdg+ 7][skey]=f2h(vv1.w);
        Vt[sdg+ 8][skey]=f2h(vv2.x); Vt[sdg+ 9][skey]=f2h(vv2.y);
        Vt[sdg+10][skey]=f2h(vv2.z); Vt[sdg+11][skey]=f2h(vv2.w);
        Vt[sdg+12][skey]=f2h(vv3.x); Vt[sdg+13][skey]=f2h(vv3.y);
        Vt[sdg+14][skey]=f2h(vv3.z); Vt[sdg+15][skey]=f2h(vv3.w);
        __syncthreads();
        if (t + 1 < t_end) {  // issue next-tile loads; latency hides under compute
            const float* kr = k + (size_t)((t+1)*64 + skey)*(KVH*HD) + kvh*HD + sdg;
            ka0 = ((const float4*)kr)[0]; ka1 = ((const float4*)kr)[1];
            ka2 = ((const float4*)kr)[2]; ka3 = ((const float4*)kr)[3];
            const float* vr = v + (size_t)((t+1)*64 + skey)*(KVH*HD) + kvh*HD + sdg;
            vv0 = ((const float4*)vr)[0]; vv1 = ((const float4*)vr)[1];
            vv2 = ((const float4*)vr)[2]; vv3 = ((const float4*)vr)[3];
        }
        const int k0 = t * 64;
        f32x4 sc[4];
        #pragma unroll
        for (int f = 0; f < 4; ++f) {
            f32x4 sf; sf[0]=0.f; sf[1]=0.f; sf[2]=0.f; sf[3]=0.f;
            f16x8 bk0 = *(const f16x8*)&Ks[f*16 + lo][hi*8];
            sf = __builtin_amdgcn_mfma_f32_16x16x32_f16(qf[0], bk0, sf, 0, 0, 0);
            f16x8 bk1 = *(const f16x8*)&Ks[f*16 + lo][32 + hi*8];
            sf = __builtin_amdgcn_mfma_f32_16x16x32_f16(qf[1], bk1, sf, 0, 0, 0);
            sc[f] = sf;
        }
        #pragma unroll
        for (int f = 0; f < 4; ++f)
            #pragma unroll
            for (int r = 0; r < 4; ++r) sc[f][r] *= 0.125f;
        if (t == qi) {   // diagonal tile: causal mask
            int qrow = q0 + wid*16 + hi*4;
            #pragma unroll
            for (int f = 0; f < 4; ++f)
                #pragma unroll
                for (int r = 0; r < 4; ++r)
                    if (k0 + f*16 + lo > qrow + r) sc[f][r] = -1e30f;
        }
        float scale_[4];
        #pragma unroll
        for (int r = 0; r < 4; ++r) {
            float x = fmaxf(fmaxf(sc[0][r], sc[1][r]), fmaxf(sc[2][r], sc[3][r]));
            x = fmaxf(x, __shfl_xor(x, 1));
            x = fmaxf(x, __shfl_xor(x, 2));
            x = fmaxf(x, __shfl_xor(x, 4));
            x = fmaxf(x, __shfl_xor(x, 8));
            float mn = fmaxf(m[r], x);
            scale_[r] = __expf(m[r] - mn);
            m[r] = mn;
            l[r] *= scale_[r];
            acc[0][r] *= scale_[r]; acc[1][r] *= scale_[r];
            acc[2][r] *= scale_[r]; acc[3][r] *= scale_[r];
        }
        float rs[4] = {0.f, 0.f, 0.f, 0.f};
        #pragma unroll
        for (int f = 0; f < 4; ++f)
            #pragma unroll
            for (int r = 0; r < 4; ++r) {
                float e = __expf(sc[f][r] - m[r]);
                rs[r] += e;
                Ps[wid][hi*4 + r][f*16 + lo] = f2h(e);
            }
        #pragma unroll
        for (int r = 0; r < 4; ++r) {
            float x = rs[r];
            x += __shfl_xor(x, 1); x += __shfl_xor(x, 2);
            x += __shfl_xor(x, 4); x += __shfl_xor(x, 8);
            l[r] += x;
        }
        asm volatile("s_waitcnt lgkmcnt(0)" ::: "memory");
        __builtin_amdgcn_sched_barrier(0);
        f16x8 pa0 = *(const f16x8*)&Ps[wid][lo][hi*8];
        f16x8 pa1 = *(const f16x8*)&Ps[wid][lo][32 + hi*8];
        #pragma unroll
        for (int f = 0; f < 4; ++f) {
            f32x4 o = acc[f];
            f16x8 v0 = *(const f16x8*)&Vt[f*16 + lo][hi*8];
            o = __builtin_amdgcn_mfma_f32_16x16x32_f16(pa0, v0, o, 0, 0, 0);
            f16x8 v1 = *(const f16x8*)&Vt[f*16 + lo][32 + hi*8];
            o = __builtin_amdgcn_mfma_f32_16x16x32_f16(pa1, v1, o, 0, 0, 0);
            acc[f] = o;
        }
    }
    const int pbase = head * 80 + s;
    float* po = pO + (size_t)pbase * 4096;
    #pragma unroll
    for (int r = 0; r < 4; ++r)
        #pragma unroll
        for (int f = 0; f < 4; ++f)
            po[(wid*16 + hi*4 + r) * 64 + f*16 + lo] = acc[f][r];
    if (lo == 0) {
        #pragma unroll
        for (int r = 0; r < 4; ++r) {
            pm[pbase*64 + wid*16 + hi*4 + r] = m[r];
            pl[pbase*64 + wid*16 + hi*4 + r] = l[r];
        }
    }
}

// ---------------- combine partials -> fp16 attention output ----------------
__global__ __launch_bounds__(256) void attn_combine_kernel(const float* __restrict__ pO,
        const float* __restrict__ pm, const float* __restrict__ pl,
        short* __restrict__ aoh) {
    const int qi = blockIdx.x, head = blockIdx.y;
    const int nch = qi / 8 + 1;
    int sbase;
    if (qi < 8)       sbase = qi;
    else if (qi < 16) sbase = 8 + (qi - 8) * 2;
    else if (qi < 24) sbase = 24 + (qi - 16) * 3;
    else              sbase = 48 + (qi - 24) * 4;
    const int row = threadIdx.x >> 2;
    const int d0 = (threadIdx.x & 3) * 16;
    float mv[4], lv[4];
    float mx = -1e30f;
    #pragma unroll
    for (int cd = 0; cd < 4; ++cd) {
        if (cd < nch) {
            int p = head * 80 + sbase + cd;
            mv[cd] = pm[p * 64 + row];
            lv[cd] = pl[p * 64 + row];
            mx = fmaxf(mx, mv[cd]);
        } else { mv[cd] = -1e30f; lv[cd] = 0.f; }
    }
    float w[4];
    float lsum = 0.f;
    #pragma unroll
    for (int cd = 0; cd < 4; ++cd) {
        w[cd] = (cd < nch) ? __expf(mv[cd] - mx) : 0.f;
        lsum += w[cd] * lv[cd];
    }
    float inv = 1.0f / lsum;
    float o[16] = {};
    #pragma unroll
    for (int cd = 0; cd < 4; ++cd) {
        if (cd < nch) {
            const float4* po = (const float4*)(pO + ((size_t)(head * 80 + sbase + cd)) * 4096 + row * 64 + d0);
            float wc = w[cd] * inv;
            #pragma unroll
            for (int j = 0; j < 4; ++j) {
                float4 vv = po[j];
                o[j*4+0] += wc * vv.x; o[j*4+1] += wc * vv.y;
                o[j*4+2] += wc * vv.z; o[j*4+3] += wc * vv.w;
            }
        }
    }
    size_t outb = (size_t)(qi * 64 + row) * HID + head * HD + d0;
    s16x8 w0, w1;
    #pragma unroll
    for (int i = 0; i < 8; ++i) { w0[i] = f2h(o[i]); w1[i] = f2h(o[8+i]); }
    *(s16x8*)(aoh + outb) = w0;
    *(s16x8*)(aoh + outb + 8) = w1;
}

// ---------------- gate + top-2 routing (exact fp32) ----------------
__global__ __launch_bounds__(64) void gate_topk_kernel(const float* __restrict__ xn,
                                                       const float* __restrict__ gw,
                                                       int* __restrict__ cnt,
                                                       int* __restrict__ idx,
                                                       float* __restrict__ wt) {
    int t = blockIdx.x, lane = threadIdx.x;
    float acc[NE] = {};
    for (int i = lane; i < HID; i += 64) {
        float x = xn[(size_t)t * HID + i];
        #pragma unroll
        for (int e = 0; e < NE; ++e) acc[e] += x * gw[e * HID + i];
    }
    #pragma unroll
    for (int e = 0; e < NE; ++e)
        for (int off = 32; off; off >>= 1) acc[e] += __shfl_xor(acc[e], off);
    if (lane == 0) {
        float mx = acc[0];
        #pragma unroll
        for (int e = 1; e < NE; ++e) mx = fmaxf(mx, acc[e]);
        float p[NE];
        #pragma unroll
        for (int e = 0; e < NE; ++e) p[e] = __expf(acc[e] - mx);
        int i0 = 0;
        #pragma unroll
        for (int e = 1; e < NE; ++e) if (p[e] > p[i0]) i0 = e;
        int i1 = -1;
        #pragma unroll
        for (int e = 0; e < NE; ++e) if (e != i0 && (i1 < 0 || p[e] > p[i1])) i1 = e;
        float w0 = p[i0], w1 = p[i1];
        float inv = 1.0f / (w0 + w1);
        int s0 = atomicAdd(&cnt[i0], 1);
        idx[i0 * S_LEN + s0] = t; wt[i0 * S_LEN + s0] = w0 * inv;
        int s1 = atomicAdd(&cnt[i1], 1);
        idx[i1 * S_LEN + s1] = t; wt[i1 * S_LEN + s1] = w1 * inv;
    }
}

// ---------------- MoE mlp1 (fp16): ab16 = fp16( silu(x@w1^T) * (x@w3^T) ) ----------------
__global__ __launch_bounds__(256) void moe_mlp1_h16(const short* __restrict__ Xh,
        const short* __restrict__ W1h, const short* __restrict__ W3h,
        const int* __restrict__ cnt, const int* __restrict__ idx,
        short* __restrict__ abh) {
    int e = blockIdx.z;
    int ne = cnt[e];
    int m0 = blockIdx.y * 128;
    if (m0 >= ne) return;
    int f0 = blockIdx.x * 64;
    __shared__ __align__(16) short As[128*40];
    __shared__ __align__(16) short Gs[64*40], Us[64*40];
    __shared__ int rows[128];
    const int tid = threadIdx.x;
    if (tid < 128) {
        int slot = m0 + tid;
        rows[tid] = (slot < ne) ? idx[e * S_LEN + slot] : 0;
    }
    __syncthreads();
    const int lane = tid & 63, lo = lane & 15, hi = lane >> 4;
    const int wid = tid >> 6, wr = wid >> 1, wc = wid & 1;
    const int srow = tid >> 2, scol = (tid & 3) * 8;
    const short* pX0 = Xh + (size_t)rows[srow] * HID + scol;
    const short* pX1 = Xh + (size_t)rows[64 + srow] * HID + scol;
    const short* p1 = W1h + ((size_t)e * FF + f0 + srow) * HID + scol;
    const short* p3 = W3h + ((size_t)e * FF + f0 + srow) * HID + scol;

    f32x4 ag[4][2], au[4][2];
    #pragma unroll
    for (int m = 0; m < 4; ++m)
        #pragma unroll
        for (int n = 0; n < 2; ++n) {
            ag[m][n][0]=0.f; ag[m][n][1]=0.f; ag[m][n][2]=0.f; ag[m][n][3]=0.f;
            au[m][n][0]=0.f; au[m][n][1]=0.f; au[m][n][2]=0.f; au[m][n][3]=0.f;
        }

    for (int k0 = 0; k0 < HID; k0 += 32) {
        s16x8 a0 = *(const s16x8*)(pX0 + k0);
        s16x8 a1 = *(const s16x8*)(pX1 + k0);
        s16x8 g0 = *(const s16x8*)(p1 + k0);
        s16x8 u0 = *(const s16x8*)(p3 + k0);
        __syncthreads();
        *(s16x8*)&As[srow*40 + scol] = a0;
        *(s16x8*)&As[(64+srow)*40 + scol] = a1;
        *(s16x8*)&Gs[srow*40 + scol] = g0;
        *(s16x8*)&Us[srow*40 + scol] = u0;
        __syncthreads();
        f16x8 aF[4], gF[2], uF[2];
        #pragma unroll
        for (int m = 0; m < 4; ++m) aF[m] = *(const f16x8*)&As[(wr*64 + m*16 + lo)*40 + hi*8];
        #pragma unroll
        for (int n = 0; n < 2; ++n) {
            gF[n] = *(const f16x8*)&Gs[(wc*32 + n*16 + lo)*40 + hi*8];
            uF[n] = *(const f16x8*)&Us[(wc*32 + n*16 + lo)*40 + hi*8];
        }
        #pragma unroll
        for (int m = 0; m < 4; ++m)
            #pragma unroll
            for (int n = 0; n < 2; ++n) {
                ag[m][n] = __builtin_amdgcn_mfma_f32_16x16x32_f16(aF[m], gF[n], ag[m][n], 0, 0, 0);
                au[m][n] = __builtin_amdgcn_mfma_f32_16x16x32_f16(aF[m], uF[n], au[m][n], 0, 0, 0);
            }
    }
    #pragma unroll
    for (int m = 0; m < 4; ++m)
        #pragma unroll
        for (int n = 0; n < 2; ++n)
            #pragma unroll
            for (int r = 0; r < 4; ++r) {
                int slot = m0 + wr*64 + m*16 + hi*4 + r;
                if (slot >= ne) continue;
                float g = ag[m][n][r], u = au[m][n][r];
                float a = g * (1.0f / (1.0f + __expf(-g))) * u;
                abh[((size_t)e * S_LEN + slot) * FF + f0 + wc*32 + n*16 + lo] = f2h(a);
            }
}

// ---------------- MoE mlp2 (fp16): h += wt * (a @ w2^T) ----------------
__global__ __launch_bounds__(256) void moe_mlp2_h16(const short* __restrict__ abh,
        const short* __restrict__ W2h,
        const int* __restrict__ cnt, const int* __restrict__ idx,
        const float* __restrict__ wt, float* __restrict__ hbuf) {
    int e = blockIdx.z;
    int ne = cnt[e];
    int m0 = blockIdx.y * 128;
    if (m0 >= ne) return;
    int n0 = blockIdx.x * 128;
    __shared__ __align__(16) short As[128*40], Bs[128*40];
    const int tid = threadIdx.x;
    const int lane = tid & 63, lo = lane & 15, hi = lane >> 4;
    const int wid = tid >> 6, wr = wid >> 1, wc = wid & 1;
    const int srow = tid >> 2, scol = (tid & 3) * 8;
    f32x4 acc[4][4];
    #pragma unroll
    for (int m = 0; m < 4; ++m)
        #pragma unroll
        for (int n = 0; n < 4; ++n) { acc[m][n][0]=0.f; acc[m][n][1]=0.f; acc[m][n][2]=0.f; acc[m][n][3]=0.f; }
    gemm128_core(abh + ((size_t)e*S_LEN + m0 + srow)*FF + scol,
                 abh + ((size_t)e*S_LEN + m0 + 64 + srow)*FF + scol,
                 W2h + ((size_t)e*HID + n0 + srow)*FF + scol,
                 W2h + ((size_t)e*HID + n0 + 64 + srow)*FF + scol,
                 FF, tid, As, Bs, acc);
    #pragma unroll
    for (int m = 0; m < 4; ++m) {
        #pragma unroll
        for (int r = 0; r < 4; ++r) {
            int slot = m0 + wr*64 + m*16 + hi*4 + r;
            if (slot >= ne) continue;
            int tok = idx[e * S_LEN + slot];
            float wv = wt[e * S_LEN + slot];
            #pragma unroll
            for (int n = 0; n < 4; ++n)
                atomicAdd(&hbuf[(size_t)tok * HID + n0 + wc*64 + n*16 + lo], acc[m][n][r] * wv);
        }
    }
}

extern "C" void kernel_launch(void* const* d_in, const int* in_sizes, int n_in,
                              void* d_out, int out_size, void* d_ws, size_t ws_size,
                              hipStream_t stream) {
    const float* emb = (const float*)d_in[0];
    const float* ln1 = (const float*)d_in[1];
    const float* ln2 = (const float*)d_in[2];
    const float* fln = (const float*)d_in[3];
    const float* qw  = (const float*)d_in[4];
    const float* kw  = (const float*)d_in[5];
    const float* vw  = (const float*)d_in[6];
    const float* ow  = (const float*)d_in[7];
    const float* gw  = (const float*)d_in[8];
    const float* w1  = (const float*)d_in[9];
    const float* w2  = (const float*)d_in[10];
    const float* w3  = (const float*)d_in[11];

    float* ws   = (float*)d_ws;
    float* h    = ws + OFF_H;
    float* xn   = ws + OFF_XN;
    float* q    = ws + OFF_Q;
    float* kb   = ws + OFF_K;
    float* vb   = ws + OFF_V;
    float* cosb = ws + OFF_COS;
    float* sinb = ws + OFF_SIN;
    float* wt   = ws + OFF_WT;
    int*   cnt  = (int*)(ws + OFF_INT);
    int*   idx  = cnt + 8;
    short* xh   = (short*)(ws + OFF_XH);
    short* aoh  = (short*)(ws + OFF_AOH);
    short* abh  = (short*)(ws + OFF_ABH);
    float* pO   = ws + OFF_PO;
    float* pm   = ws + OFF_PM;
    float* pl   = ws + OFF_PL;
    short* WC   = (short*)(ws + OFF_WCVT);

    // converted weights (fp16), non-overlapping
    short* sq = WC;
    short* sk = sq + HID*HID;
    short* sv = sk + KVH*HD*HID;
    short* so = sv + KVH*HD*HID;
    short* s1 = so + HID*HID;
    short* s3 = s1 + (size_t)NE*FF*HID;
    short* s2 = s3 + (size_t)NE*FF*HID;

    hipMemcpyAsync(h, emb, (size_t)S_LEN * HID * sizeof(float), hipMemcpyDeviceToDevice, stream);
    rope_tables_kernel<<<S_LEN * 32 / 256, 256, 0, stream>>>(cosb, sinb);

    const int n8_qo = HID*HID/8, n8_kv = KVH*HD*HID/8, n8_w = NE*FF*HID/8;

    for (int l = 0; l < NL; ++l) {
        cvt16_kernel<<<n8_qo/256, 256, 0, stream>>>(qw + (size_t)l*HID*HID, sq, n8_qo);
        cvt16_kernel<<<n8_kv/256, 256, 0, stream>>>(kw + (size_t)l*KVH*HD*HID, sk, n8_kv);
        cvt16_kernel<<<n8_kv/256, 256, 0, stream>>>(vw + (size_t)l*KVH*HD*HID, sv, n8_kv);
        cvt16_kernel<<<n8_qo/256, 256, 0, stream>>>(ow + (size_t)l*HID*HID, so, n8_qo);

        rmsnorm_h16_kernel<<<S_LEN, 256, 0, stream>>>(h, ln1 + l * HID, xn, xh);
        qkv_h16_kernel<<<dim3(12, 16), 256, 0, stream>>>(xh, sq, sk, sv, q, kb, vb);
        rope_apply_kernel<<<(S_LEN * NHEAD * 32) / 256, 256, 0, stream>>>(q, cosb, sinb, NHEAD, S_LEN * NHEAD * 32);
        rope_apply_kernel<<<(S_LEN * KVH * 32) / 256, 256, 0, stream>>>(kb, cosb, sinb, KVH, S_LEN * KVH * 32);
        attn_mfma_kernel<<<dim3(80, NHEAD), 256, 0, stream>>>(q, kb, vb, pO, pm, pl);
        attn_combine_kernel<<<dim3(32, NHEAD), 256, 0, stream>>>(pO, pm, pl, aoh);
        gemm_h16_kernel<<<dim3(8, 16), 256, 0, stream>>>(aoh, so, h, h, HID, HID);

        rmsnorm_h16_kernel<<<S_LEN, 256, 0, stream>>>(h, ln2 + l * HID, xn, xh);
        hipMemsetAsync(cnt, 0, 8 * sizeof(int), stream);
        gate_topk_kernel<<<S_LEN, 64, 0, stream>>>(xn, gw + (size_t)l * NE * HID, cnt, idx, wt);

        cvt16_kernel<<<n8_w/256, 256, 0, stream>>>(w1 + (size_t)l*NE*FF*HID, s1, n8_w);
        cvt16_kernel<<<n8_w/256, 256, 0, stream>>>(w3 + (size_t)l*NE*FF*HID, s3, n8_w);
        moe_mlp1_h16<<<dim3(16, 16, 8), 256, 0, stream>>>(xh, s1, s3, cnt, idx, abh);

        cvt16_kernel<<<n8_w/256, 256, 0, stream>>>(w2 + (size_t)l*NE*HID*FF, s2, n8_w);
        moe_mlp2_h16<<<dim3(8, 16, 8), 256, 0, stream>>>(abh, s2, cnt, idx, wt, h);
    }
    rmsnorm_kernel<<<S_LEN, 256, 0, stream>>>(h, fln, (float*)d_out);
}